// Round 2
// baseline (776.408 us; speedup 1.0000x reference)
//
#include <hip/hip_runtime.h>
#include <hip/hip_bf16.h>

// GCN + MultiHead GAT + TCN, fp32 baseline.
// B=16, N=1024, NFEAT=128, NHID=256, NOUT=256, H=4, DH=64.
//
// Pipeline / buffer flow (A = ws region, OUT = d_out used as scratch):
//   pack:   gat_w -> W2[f][c], conv_w -> CW[kz*256+ci][co]   (ws)
//   gemm0:  h1t[m][b*256+o] = x @ gc_w                        -> A
//   gemm1:  g[b][n][o] = relu(adj @ h1t + gc_b)               -> OUT
//   bn1:    stats over (b,n) per o; apply in-place + relu     on OUT
//   gemm2:  hp[b][n][c] = g @ W2                              -> A
//   flash:  per (b,h): softmax(lrelu(hp hp^T)) @ hp           -> OUT
//   gemm3:  y[b][n][co] = im2col(gat) @ CW + conv_b           -> A
//   bn2:    stats; apply + relu                               -> OUT (final)

static __device__ __forceinline__ float4 ld4(const float* p){ return *(const float4*)p; }
static __device__ __forceinline__ void st4(float* p, float4 v){ *(float4*)p = v; }

// ---------------------------------------------------------------- GEMM
// MODE 0: x(16384x128) @ gc_w(128x256)       -> h1t scatter [(m*16+b)*256+o]
// MODE 1: adj(1024x1024) @ h1t(1024x4096)    -> +bias, relu, scatter [(b*1024+n)*256+o]
// MODE 2: g(16384x256) @ W2(256x256)         -> hp row-major
// MODE 3: im2col(gat)(16384x768) @ CW(768x256) -> +conv_b, row-major
template<int MODE>
__global__ __launch_bounds__(256, 2) void gemm_k(const float* __restrict__ A,
                                                 const float* __restrict__ B,
                                                 float* __restrict__ C,
                                                 const float* __restrict__ bias)
{
  constexpr int K  = (MODE==0)?128:(MODE==1)?1024:(MODE==2)?256:768;
  constexpr int NN = (MODE==1)?4096:256;
  constexpr int KT = K/8;
  __shared__ float Asm[8][132];   // [k][row], transposed, pad keeps b128 2-way max
  __shared__ float Bsm[8][132];   // [k][col]
  const int tid = threadIdx.x;
  const int n0 = blockIdx.x*128;
  const int m0 = blockIdx.y*128;
  const int tr = tid>>4, tc = tid&15;          // 8x8 register tile owner
  const int lrow = tid>>1, lpart = tid&1;      // A staging: 128 rows x 2 half-rows
  const int lkrow = tid>>5, lseg = tid&31;     // B staging: 8 rows x 32 segs

  float acc[8][8];
#pragma unroll
  for (int i=0;i<8;i++)
#pragma unroll
    for (int j=0;j<8;j++) acc[i][j]=0.f;

  auto loadA = [&](int kt) -> float4 {
    const int k0 = kt*8;
    if constexpr (MODE==3) {
      const int kz  = k0 >> 8;           // conv tap 0..2
      const int ci0 = k0 & 255;
      const int R   = m0 + lrow;         // flat row b*1024+n
      const int ns  = (R & 1023) + kz - 1;
      if ((unsigned)ns < 1024u)
        return ld4(A + (size_t)(R + kz - 1)*256 + ci0 + lpart*4);
      return float4{0.f,0.f,0.f,0.f};
    } else {
      return ld4(A + (size_t)(m0+lrow)*K + k0 + lpart*4);
    }
  };
  auto loadB = [&](int kt) -> float4 {
    const int k0 = kt*8;
    return ld4(B + (size_t)(k0+lkrow)*NN + n0 + lseg*4);
  };

  float4 av = loadA(0);
  float4 bv = loadB(0);

  for (int kt=0; kt<KT; ++kt) {
    __syncthreads();
    Asm[lpart*4+0][lrow] = av.x;
    Asm[lpart*4+1][lrow] = av.y;
    Asm[lpart*4+2][lrow] = av.z;
    Asm[lpart*4+3][lrow] = av.w;
    st4(&Bsm[lkrow][lseg*4], bv);
    __syncthreads();
    if (kt+1 < KT) { av = loadA(kt+1); bv = loadB(kt+1); }  // overlap next tile
#pragma unroll
    for (int kk=0;kk<8;kk++) {
      const float4 a0 = ld4(&Asm[kk][tr*8]);
      const float4 a1 = ld4(&Asm[kk][tr*8+4]);
      const float4 b0 = ld4(&Bsm[kk][tc*8]);
      const float4 b1 = ld4(&Bsm[kk][tc*8+4]);
      const float a[8] = {a0.x,a0.y,a0.z,a0.w,a1.x,a1.y,a1.z,a1.w};
      const float b[8] = {b0.x,b0.y,b0.z,b0.w,b1.x,b1.y,b1.z,b1.w};
#pragma unroll
      for (int i=0;i<8;i++)
#pragma unroll
        for (int j=0;j<8;j++)
          acc[i][j] = fmaf(a[i], b[j], acc[i][j]);
    }
  }

  const int c0 = n0 + tc*8;
  if constexpr (MODE==0) {
#pragma unroll
    for (int i=0;i<8;i++) {
      const int R = m0 + tr*8 + i;
      const int nn_ = R & 1023, bb = R >> 10;
      float* cp = C + (size_t)(nn_*16 + bb)*256 + c0;   // h1t[m][b*256+o]
      st4(cp,   float4{acc[i][0],acc[i][1],acc[i][2],acc[i][3]});
      st4(cp+4, float4{acc[i][4],acc[i][5],acc[i][6],acc[i][7]});
    }
  } else if constexpr (MODE==1) {
    const int bb = c0 >> 8, oo = c0 & 255;   // 8-aligned chunk never crosses a 256 boundary
    const float4 g0 = ld4(bias + oo);
    const float4 g1 = ld4(bias + oo + 4);
    const float bs[8] = {g0.x,g0.y,g0.z,g0.w,g1.x,g1.y,g1.z,g1.w};
#pragma unroll
    for (int i=0;i<8;i++) {
      const int nn_ = m0 + tr*8 + i;
      float* cp = C + ((size_t)bb*1024 + nn_)*256 + oo;
      float v[8];
#pragma unroll
      for (int j=0;j<8;j++) v[j] = fmaxf(acc[i][j] + bs[j], 0.f);
      st4(cp,   float4{v[0],v[1],v[2],v[3]});
      st4(cp+4, float4{v[4],v[5],v[6],v[7]});
    }
  } else if constexpr (MODE==2) {
#pragma unroll
    for (int i=0;i<8;i++) {
      float* cp = C + (size_t)(m0 + tr*8 + i)*256 + c0;
      st4(cp,   float4{acc[i][0],acc[i][1],acc[i][2],acc[i][3]});
      st4(cp+4, float4{acc[i][4],acc[i][5],acc[i][6],acc[i][7]});
    }
  } else {  // MODE 3
    const float4 g0 = ld4(bias + c0);
    const float4 g1 = ld4(bias + c0 + 4);
    const float bs[8] = {g0.x,g0.y,g0.z,g0.w,g1.x,g1.y,g1.z,g1.w};
#pragma unroll
    for (int i=0;i<8;i++) {
      float* cp = C + (size_t)(m0 + tr*8 + i)*256 + c0;
      float v[8];
#pragma unroll
      for (int j=0;j<8;j++) v[j] = acc[i][j] + bs[j];
      st4(cp,   float4{v[0],v[1],v[2],v[3]});
      st4(cp+4, float4{v[4],v[5],v[6],v[7]});
    }
  }
}

// ---------------------------------------------------------------- flash GAT
// One thread = one query row (64 f32 in regs). Keys/values are the same
// matrix; tile of 64 keys staged in LDS, each key's 64 floats pulled to regs
// (broadcast reads), dot -> leakyrelu -> exp(s-40) -> accumulate U,l.
// No running max needed: by Cauchy-Schwarz e[n][m] <= max_n ||hp_n||^2
// (~32-45 here), and the diagonal e>=0 keeps the row sum >= exp(-40):
// exp(s-40) can neither overflow nor lose the max term. Exact softmax.
__global__ __launch_bounds__(256, 1) void flash_gat(const float* __restrict__ hp,
                                                    float* __restrict__ outp)
{
  __shared__ float Ksm[64][68];
  const int bid = blockIdx.x;          // 256 = 16 b * 4 h * 4 row-quarters
  const int b  = bid >> 4;
  const int h  = (bid >> 2) & 3;
  const int qq = bid & 3;
  const int t  = threadIdx.x;
  const int n  = qq*256 + t;
  const float* base = hp + (size_t)b*1024*256 + h*64;

  float4 q[16], u[16];
  {
    const float* qp = base + (size_t)n*256;
#pragma unroll
    for (int j=0;j<16;j++) { q[j] = ld4(qp + j*4); u[j] = float4{0.f,0.f,0.f,0.f}; }
  }
  float l = 0.f;

  const int row = t >> 2, part = t & 3;
  for (int kt=0; kt<16; ++kt) {
    const float* kp = base + (size_t)(kt*64 + row)*256 + part*4;
#pragma unroll
    for (int j=0;j<4;j++) {
      const float4 v = ld4(kp + j*16);
      st4(&Ksm[row][(part + j*4)*4], v);
    }
    __syncthreads();
    for (int m=0;m<64;m++) {
      float4 kk[16];
#pragma unroll
      for (int j=0;j<16;j++) kk[j] = ld4(&Ksm[m][j*4]);
      float s0=0.f,s1=0.f,s2=0.f,s3=0.f;
#pragma unroll
      for (int j=0;j<16;j++) {
        s0 = fmaf(q[j].x, kk[j].x, s0);
        s1 = fmaf(q[j].y, kk[j].y, s1);
        s2 = fmaf(q[j].z, kk[j].z, s2);
        s3 = fmaf(q[j].w, kk[j].w, s3);
      }
      float s = (s0+s1)+(s2+s3);
      s = s > 0.f ? s : 0.2f*s;          // LeakyReLU(0.2)
      const float p = __expf(s - 40.f);  // fixed-shift softmax numerator
      l += p;
#pragma unroll
      for (int j=0;j<16;j++) {
        u[j].x = fmaf(p, kk[j].x, u[j].x);
        u[j].y = fmaf(p, kk[j].y, u[j].y);
        u[j].z = fmaf(p, kk[j].z, u[j].z);
        u[j].w = fmaf(p, kk[j].w, u[j].w);
      }
    }
    __syncthreads();
  }
  const float inv = 1.0f / l;
  float* op = outp + ((size_t)b*1024 + n)*256 + h*64;
#pragma unroll
  for (int j=0;j<16;j++) {
    float4 v;
    v.x = u[j].x*inv; v.y = u[j].y*inv; v.z = u[j].z*inv; v.w = u[j].w*inv;
    st4(op + j*4, v);
  }
}

// ---------------------------------------------------------------- BN helpers
// Stage 1: 256 blocks x 64 rows -> per-block per-channel sum/sumsq.
__global__ __launch_bounds__(256) void bn_partial(const float* __restrict__ buf,
                                                  float* __restrict__ part)
{
  const int bi = blockIdx.x, t = threadIdx.x;
  const float* p = buf + (size_t)bi*64*256 + t;
  float s=0.f, q=0.f;
#pragma unroll 4
  for (int r=0;r<64;r++) { const float v = p[(size_t)r*256]; s += v; q = fmaf(v,v,q); }
  part[bi*512 + t]       = s;
  part[bi*512 + 256 + t] = q;
}

// Stage 2: fold 256 partials, emit per-channel {mu, rsqrt(var+eps)*gamma, beta}.
__global__ __launch_bounds__(256) void bn_final(const float* __restrict__ part,
                                                const float* __restrict__ gamma,
                                                const float* __restrict__ beta,
                                                float* __restrict__ prm)
{
  const int t = threadIdx.x;
  float s=0.f, q=0.f;
#pragma unroll 8
  for (int i=0;i<256;i++) { s += part[i*512+t]; q += part[i*512+256+t]; }
  const float mu  = s * (1.f/16384.f);
  const float var = q * (1.f/16384.f) - mu*mu;
  prm[t]       = mu;
  prm[256 + t] = rsqrtf(var + 1e-5f) * gamma[t];
  prm[512 + t] = beta[t];
}

// Elementwise BN + ReLU (in==outp allowed).
__global__ __launch_bounds__(256) void bn_apply(const float* __restrict__ in,
                                                float* __restrict__ outp,
                                                const float* __restrict__ prm)
{
  const int idx = blockIdx.x*256 + threadIdx.x;
  const size_t off = (size_t)idx * 8;
  const int o = (int)(off & 255);
  const float4 x0 = ld4(in + off),      x1 = ld4(in + off + 4);
  const float4 m0 = ld4(prm + o),       m1 = ld4(prm + o + 4);
  const float4 r0 = ld4(prm + 256 + o), r1 = ld4(prm + 256 + o + 4);
  const float4 b0 = ld4(prm + 512 + o), b1 = ld4(prm + 512 + o + 4);
  float4 y0, y1;
  y0.x = fmaxf(fmaf(x0.x - m0.x, r0.x, b0.x), 0.f);
  y0.y = fmaxf(fmaf(x0.y - m0.y, r0.y, b0.y), 0.f);
  y0.z = fmaxf(fmaf(x0.z - m0.z, r0.z, b0.z), 0.f);
  y0.w = fmaxf(fmaf(x0.w - m0.w, r0.w, b0.w), 0.f);
  y1.x = fmaxf(fmaf(x1.x - m1.x, r1.x, b1.x), 0.f);
  y1.y = fmaxf(fmaf(x1.y - m1.y, r1.y, b1.y), 0.f);
  y1.z = fmaxf(fmaf(x1.z - m1.z, r1.z, b1.z), 0.f);
  y1.w = fmaxf(fmaf(x1.w - m1.w, r1.w, b1.w), 0.f);
  st4(outp + off, y0);
  st4(outp + off + 4, y1);
}

// ---------------------------------------------------------------- weight pack
// W2[f*256 + (h*64+d)] = gat_w[h][f][d];  CW[(kz*256+ci)*256+co] = conv_w[co][ci][kz]
__global__ __launch_bounds__(256) void pack_w(const float* __restrict__ gw,
                                              const float* __restrict__ cw,
                                              float* __restrict__ W2,
                                              float* __restrict__ CW)
{
  const int idx = blockIdx.x*256 + threadIdx.x;
  if (idx < 65536) {
    const int f = idx >> 8, c = idx & 255;
    W2[idx] = gw[((c>>6)<<14) + (f<<6) + (c&63)];
  }
  if (idx < 196608) {
    const int co = idx & 255;
    const int rest = idx >> 8;
    const int ci = rest & 255, kz = rest >> 8;
    CW[idx] = cw[co*768 + ci*3 + kz];
  }
}

// ---------------------------------------------------------------- launch
extern "C" void kernel_launch(void* const* d_in, const int* in_sizes, int n_in,
                              void* d_out, int out_size, void* d_ws, size_t ws_size,
                              hipStream_t stream)
{
  const float* x     = (const float*)d_in[0];
  const float* adj   = (const float*)d_in[1];
  const float* gc_w  = (const float*)d_in[2];
  const float* gc_b  = (const float*)d_in[3];
  const float* bn1g  = (const float*)d_in[4];
  const float* bn1b  = (const float*)d_in[5];
  const float* gatw  = (const float*)d_in[6];
  const float* convw = (const float*)d_in[7];
  const float* convb = (const float*)d_in[8];
  const float* bn2g  = (const float*)d_in[9];
  const float* bn2b  = (const float*)d_in[10];
  float* out = (float*)d_out;
  char*  ws  = (char*)d_ws;

  // ws layout (bytes): [A 16 MiB][W2 256K][CW 768K][P1 512K][P2 512K][PR1 4K][PR2 4K]
  float* bufA = (float*)(ws + 0);
  float* W2   = (float*)(ws + 16777216);
  float* CW   = (float*)(ws + 17039360);
  float* P1   = (float*)(ws + 17825792);
  float* P2   = (float*)(ws + 18350080);
  float* PR1  = (float*)(ws + 18874368);
  float* PR2  = (float*)(ws + 18878464);

  pack_w<<<768, 256, 0, stream>>>(gatw, convw, W2, CW);
  gemm_k<0><<<dim3(2,128), 256, 0, stream>>>(x, gc_w, bufA, nullptr);       // h1t -> A
  gemm_k<1><<<dim3(32,8),  256, 0, stream>>>(adj, bufA, out, gc_b);         // g -> OUT
  bn_partial<<<256, 256, 0, stream>>>(out, P1);
  bn_final<<<1, 256, 0, stream>>>(P1, bn1g, bn1b, PR1);
  bn_apply<<<2048, 256, 0, stream>>>(out, out, PR1);                        // BN1+relu in place
  gemm_k<2><<<dim3(2,128), 256, 0, stream>>>(out, W2, bufA, nullptr);       // hp -> A
  flash_gat<<<256, 256, 0, stream>>>(bufA, out);                            // gat -> OUT
  gemm_k<3><<<dim3(2,128), 256, 0, stream>>>(out, CW, bufA, convb);         // y -> A
  bn_partial<<<256, 256, 0, stream>>>(bufA, P2);
  bn_final<<<1, 256, 0, stream>>>(P2, bn2g, bn2b, PR2);
  bn_apply<<<2048, 256, 0, stream>>>(bufA, out, PR2);                       // final -> OUT
}

// Round 5
// 338.839 us; speedup vs baseline: 2.2914x; 2.2914x over previous
//
#include <hip/hip_runtime.h>
#include <hip/hip_bf16.h>

// GCN + MultiHead GAT + TCN — bf16 MFMA pipeline with split-precision paths.
// B=16, N=1024, NFEAT=128, NHID=256, NOUT=256, H=4, DH=64.
//
// Precision plan (BN1 amplifies pre-BN errors ~100x; exp amplifies e-errors):
//   gemm0 (x@W0):        plain bf16 MFMA (error attenuated by adj-avg + BN mean-removal)
//   gemm1 (adj@h1):      SPLIT bf16 (hi/lo both sides, 3 MFMA) -> fp32-like
//   gemm2 (h@W2):        SPLIT bf16 -> hp accurate, emitted as hi/lo pair (+ hp^T for V)
//   flash QK^T:          SPLIT bf16 (q,k hi/lo) -> e accurate; fixed-shift exp(s-40)
//   flash PV:            plain bf16 (P in [0,1], sum=1: no amplification)
//   gemm3 (conv im2col): plain bf16
// MFMA: v_mfma_f32_16x16x32_bf16. Frag layouts (guide m89-verified D; standard A/B):
//   A[row=l&15][k=(l>>4)*8+i], B[col=l&15][k=(l>>4)*8+i] (BT storage), D[col=l&15][row=(l>>4)*4+reg]
// LDS tile layout [k/8][row][8] (16B/slot) -> conflict-free ds_read_b128; staged via
// global_load_lds(16B) with per-lane permuted global source (m173 pattern).
//
// NOTE round 4: template __global__ kernels produced undefined __device_stub__
// symbols at dlopen (hipcc linkonce stub dropped for implicitly-instantiated
// template kernels in a .so). Fix: non-template __global__ wrappers forwarding
// to a __device__ template body.

typedef unsigned short u16;
typedef __attribute__((ext_vector_type(8))) short short8;  // 8 bf16 = 4 VGPR
typedef __attribute__((ext_vector_type(4))) float f32x4;

static __device__ __forceinline__ float4 ld4(const float* p){ return *(const float4*)p; }
static __device__ __forceinline__ void st4(float* p, float4 v){ *(float4*)p = v; }

static __device__ __forceinline__ u16 f2bf(float f){           // RNE
  unsigned u = __builtin_bit_cast(unsigned, f);
  unsigned r = u + 0x7FFFu + ((u >> 16) & 1u);
  return (u16)(r >> 16);
}
static __device__ __forceinline__ float bf2f(u16 h){
  unsigned u = ((unsigned)h) << 16; return __builtin_bit_cast(float, u);
}
static __device__ __forceinline__ void st4bf(u16* p, u16 a, u16 b, u16 c, u16 d){
  uint2 v; v.x = (unsigned)a | ((unsigned)b << 16); v.y = (unsigned)c | ((unsigned)d << 16);
  *(uint2*)p = v;
}
static __device__ __forceinline__ f32x4 mfma16(short8 a, short8 b, f32x4 c){
  return __builtin_amdgcn_mfma_f32_16x16x32_bf16(a, b, c, 0, 0, 0);
}

// ---------------------------------------------------------------- MFMA GEMM body
// A [M][K] bf16 row-major (hi/lo), B as BT [NN][K] bf16 (hi/lo).
// MODE 0: gemm0 -> h1t hi/lo scatter [bo][node]
// MODE 1: gemm1 -> g fp32 [(b*1024+n)*256+o], +gc_b, relu
// MODE 2: gemm2 -> hp hi/lo [R][256] + hpT (hi) [256][16384]
// MODE 3: gemm3 (A = im2col(ao), zero-pad via zbuf) -> y fp32 + conv_b
template<int SPLIT, int K, int NN, int MODE>
static __device__ __forceinline__ void mgemm_body(
    const u16* __restrict__ Ah_, const u16* __restrict__ Al_,
    const u16* __restrict__ Bh_, const u16* __restrict__ Bl_,
    const u16* __restrict__ zbuf,
    void* __restrict__ C0v, void* __restrict__ C1v, void* __restrict__ C2v,
    const float* __restrict__ bias)
{
  constexpr int KT = K / 32;
  __shared__ u16 Ah[4096], Bh[4096];
  __shared__ u16 Al[SPLIT == 3 ? 4096 : 8], Bl[SPLIT == 3 ? 4096 : 8];
  const int tid = threadIdx.x;
  const int n0 = blockIdx.x * 128, m0 = blockIdx.y * 128;
  const int lane = tid & 63, l15 = lane & 15, lq = lane >> 4;
  const int w = tid >> 6, wr = w >> 1, wc = w & 1;

  f32x4 acc[4][4] = {};

  for (int kt = 0; kt < KT; ++kt){
    const int k0 = kt * 32;
#pragma unroll
    for (int r = 0; r < 2; ++r){
      const int slot = r * 256 + tid;
      const int row = slot & 127, kh = slot >> 7;
      const int ldsoff = (r * 256 + (tid & 192)) * 8;   // wave-uniform base slot*8
      const u16* asrc;
      if constexpr (MODE == 3){
        const int kz = k0 >> 8;
        const int ci0 = (k0 & 255) + kh * 8;
        const int R = m0 + row;
        const int nn = (R & 1023) + kz - 1;
        asrc = ((unsigned)nn < 1024u) ? (Ah_ + (size_t)(R + kz - 1) * 256 + ci0) : zbuf;
      } else {
        asrc = Ah_ + (size_t)(m0 + row) * K + k0 + kh * 8;
      }
      __builtin_amdgcn_global_load_lds(asrc, &Ah[ldsoff], 16, 0, 0);
      const u16* bsrc = Bh_ + (size_t)(n0 + row) * K + k0 + kh * 8;
      __builtin_amdgcn_global_load_lds(bsrc, &Bh[ldsoff], 16, 0, 0);
      if constexpr (SPLIT == 3){
        const u16* asrc2 = Al_ + (size_t)(m0 + row) * K + k0 + kh * 8;
        __builtin_amdgcn_global_load_lds(asrc2, &Al[ldsoff], 16, 0, 0);
        const u16* bsrc2 = Bl_ + (size_t)(n0 + row) * K + k0 + kh * 8;
        __builtin_amdgcn_global_load_lds(bsrc2, &Bl[ldsoff], 16, 0, 0);
      }
    }
    __syncthreads();
    short8 afh[4], bfh[4], afl[4], bfl[4];
#pragma unroll
    for (int f = 0; f < 4; ++f){
      afh[f] = *(const short8*)&Ah[(lq * 128 + wr * 64 + f * 16 + l15) * 8];
      bfh[f] = *(const short8*)&Bh[(lq * 128 + wc * 64 + f * 16 + l15) * 8];
      if constexpr (SPLIT == 3){
        afl[f] = *(const short8*)&Al[(lq * 128 + wr * 64 + f * 16 + l15) * 8];
        bfl[f] = *(const short8*)&Bl[(lq * 128 + wc * 64 + f * 16 + l15) * 8];
      }
    }
#pragma unroll
    for (int fi = 0; fi < 4; ++fi)
#pragma unroll
      for (int fj = 0; fj < 4; ++fj){
        acc[fi][fj] = mfma16(afh[fi], bfh[fj], acc[fi][fj]);
        if constexpr (SPLIT == 3){
          acc[fi][fj] = mfma16(afl[fi], bfh[fj], acc[fi][fj]);
          acc[fi][fj] = mfma16(afh[fi], bfl[fj], acc[fi][fj]);
        }
      }
    __syncthreads();
  }

  const int rb = m0 + wr * 64;
  const int cb = n0 + wc * 64;
  if constexpr (MODE == 0){
    u16* H = (u16*)C0v; u16* L = (u16*)C1v;
#pragma unroll
    for (int fi = 0; fi < 4; ++fi){
      const int R = rb + fi * 16 + lq * 4;
      const int nn = R & 1023, bq = R >> 10;
#pragma unroll
      for (int fj = 0; fj < 4; ++fj){
        const int c = cb + fj * 16 + l15;
        const size_t off = (size_t)(bq * 256 + c) * 1024 + nn;
        u16 h_[4], l_[4];
#pragma unroll
        for (int r = 0; r < 4; ++r){
          float v = acc[fi][fj][r];
          u16 hi = f2bf(v); h_[r] = hi; l_[r] = f2bf(v - bf2f(hi));
        }
        st4bf(H + off, h_[0], h_[1], h_[2], h_[3]);
        st4bf(L + off, l_[0], l_[1], l_[2], l_[3]);
      }
    }
  } else if constexpr (MODE == 1){
    float* G = (float*)C0v;
#pragma unroll
    for (int fj = 0; fj < 4; ++fj){
      const int c = cb + fj * 16 + l15;          // bo
      const int o = c & 255, bq = c >> 8;
      const float bs = bias[o];
#pragma unroll
      for (int fi = 0; fi < 4; ++fi){
        const int R = rb + fi * 16 + lq * 4;     // node n
#pragma unroll
        for (int r = 0; r < 4; ++r)
          G[((size_t)bq * 1024 + R + r) * 256 + o] = fmaxf(acc[fi][fj][r] + bs, 0.f);
      }
    }
  } else if constexpr (MODE == 2){
    u16* H = (u16*)C0v; u16* L = (u16*)C1v; u16* T = (u16*)C2v;
#pragma unroll
    for (int fi = 0; fi < 4; ++fi){
      const int R = rb + fi * 16 + lq * 4;
#pragma unroll
      for (int fj = 0; fj < 4; ++fj){
        const int c = cb + fj * 16 + l15;
        u16 h_[4];
#pragma unroll
        for (int r = 0; r < 4; ++r){
          float v = acc[fi][fj][r];
          u16 hi = f2bf(v); h_[r] = hi;
          H[(size_t)(R + r) * 256 + c] = hi;
          L[(size_t)(R + r) * 256 + c] = f2bf(v - bf2f(hi));
        }
        st4bf(T + (size_t)c * 16384 + R, h_[0], h_[1], h_[2], h_[3]);
      }
    }
  } else {
    float* Y = (float*)C0v;
#pragma unroll
    for (int fj = 0; fj < 4; ++fj){
      const int c = cb + fj * 16 + l15;
      const float bs = bias[c];
#pragma unroll
      for (int fi = 0; fi < 4; ++fi){
        const int R = rb + fi * 16 + lq * 4;
#pragma unroll
        for (int r = 0; r < 4; ++r)
          Y[(size_t)(R + r) * 256 + c] = acc[fi][fj][r] + bs;
      }
    }
  }
}

// Non-template wrappers (hipcc emits stubs reliably for these).
__global__ __launch_bounds__(256) void gemm0_k(
    const u16* __restrict__ Ah_, const u16* __restrict__ Bh_,
    const u16* __restrict__ zbuf, void* __restrict__ C0, void* __restrict__ C1)
{ mgemm_body<1, 128, 256, 0>(Ah_, nullptr, Bh_, nullptr, zbuf, C0, C1, nullptr, nullptr); }

__global__ __launch_bounds__(256) void gemm1_k(
    const u16* __restrict__ Ah_, const u16* __restrict__ Al_,
    const u16* __restrict__ Bh_, const u16* __restrict__ Bl_,
    const u16* __restrict__ zbuf, void* __restrict__ C0, const float* __restrict__ bias)
{ mgemm_body<3, 1024, 4096, 1>(Ah_, Al_, Bh_, Bl_, zbuf, C0, nullptr, nullptr, bias); }

__global__ __launch_bounds__(256) void gemm2_k(
    const u16* __restrict__ Ah_, const u16* __restrict__ Al_,
    const u16* __restrict__ Bh_, const u16* __restrict__ Bl_,
    const u16* __restrict__ zbuf,
    void* __restrict__ C0, void* __restrict__ C1, void* __restrict__ C2)
{ mgemm_body<3, 256, 256, 2>(Ah_, Al_, Bh_, Bl_, zbuf, C0, C1, C2, nullptr); }

__global__ __launch_bounds__(256) void gemm3_k(
    const u16* __restrict__ Ah_, const u16* __restrict__ Bh_,
    const u16* __restrict__ zbuf, void* __restrict__ C0, const float* __restrict__ bias)
{ mgemm_body<1, 768, 256, 3>(Ah_, nullptr, Bh_, nullptr, zbuf, C0, nullptr, nullptr, bias); }

// ---------------------------------------------------------------- flash GAT (MFMA)
// Block = (b, h, q-quarter): 4 waves x 64 q-rows. Q hi/lo frags in regs.
// Per 64-kv tile: stage K hi/lo [dk][kv][8] + V^T [kk][d][8]; QK^T split (6 MFMA/cell);
// softmax numerator p=exp(s-40) (exact: e bounded by max||hp||^2 ~50, diag>=0);
// P -> per-wave LDS [kk][q][8]; swapped PV: out^T[d][q] += Vt(A) x P(B). 128 MFMA/wave/tile.
__global__ __launch_bounds__(256) void flash(
    const u16* __restrict__ hp_hi, const u16* __restrict__ hp_lo,
    const u16* __restrict__ hpT, u16* __restrict__ ao)
{
  __shared__ u16 Khi[4096], Klo[4096], Vt[4096];
  __shared__ u16 Pl[4][4096];
  __shared__ float Ls[4][64];
  const int tid = threadIdx.x;
  const int lane = tid & 63, l15 = lane & 15, lq = lane >> 4, w = tid >> 6;
  const int bid = blockIdx.x;
  const int b = bid >> 4, h = (bid >> 2) & 3, qq = bid & 3;
  const size_t qrow0 = (size_t)b * 1024 + qq * 256 + w * 64;

  short8 qh[4][2], ql[4][2];
#pragma unroll
  for (int fi = 0; fi < 4; ++fi)
#pragma unroll
    for (int ks = 0; ks < 2; ++ks){
      const size_t off = (qrow0 + fi * 16 + l15) * 256 + h * 64 + ks * 32 + lq * 8;
      qh[fi][ks] = *(const short8*)(hp_hi + off);
      ql[fi][ks] = *(const short8*)(hp_lo + off);
    }

  f32x4 o_[4][4] = {};   // out^T acc: [df][qf]
  float ls[16] = {};     // row-sum partials: [mf*4+r]

  for (int kt = 0; kt < 16; ++kt){
    const int kv0 = kt * 64;
#pragma unroll
    for (int r = 0; r < 2; ++r){
      const int slot = r * 256 + tid;
      const int g1 = slot >> 6, g2 = slot & 63;     // [g1][g2] of 8x64
      const int ldsoff = (r * 256 + (tid & 192)) * 8;
      const u16* ksrc = hp_hi + ((size_t)b * 1024 + kv0 + g2) * 256 + h * 64 + g1 * 8;
      __builtin_amdgcn_global_load_lds(ksrc, &Khi[ldsoff], 16, 0, 0);
      const u16* ksrc2 = hp_lo + ((size_t)b * 1024 + kv0 + g2) * 256 + h * 64 + g1 * 8;
      __builtin_amdgcn_global_load_lds(ksrc2, &Klo[ldsoff], 16, 0, 0);
      const u16* vsrc = hpT + (size_t)(h * 64 + g2) * 16384 + b * 1024 + kv0 + g1 * 8;
      __builtin_amdgcn_global_load_lds(vsrc, &Vt[ldsoff], 16, 0, 0);
    }
    __syncthreads();

    // QK^T + softmax numerator + P write
#pragma unroll
    for (int nf = 0; nf < 4; ++nf){
      short8 kf[2], kg[2];
#pragma unroll
      for (int ks = 0; ks < 2; ++ks){
        kf[ks] = *(const short8*)&Khi[((ks * 4 + lq) * 64 + nf * 16 + l15) * 8];
        kg[ks] = *(const short8*)&Klo[((ks * 4 + lq) * 64 + nf * 16 + l15) * 8];
      }
      const int kv = nf * 16 + l15;
#pragma unroll
      for (int mf = 0; mf < 4; ++mf){
        f32x4 s = {};
#pragma unroll
        for (int ks = 0; ks < 2; ++ks){
          s = mfma16(qh[mf][ks], kf[ks], s);
          s = mfma16(ql[mf][ks], kf[ks], s);
          s = mfma16(qh[mf][ks], kg[ks], s);
        }
        const int qb = mf * 16 + lq * 4;
        const int base = ((kv >> 3) * 64 + qb) * 8 + (kv & 7);
#pragma unroll
        for (int r = 0; r < 4; ++r){
          float v = s[r];
          v = v > 0.f ? v : 0.2f * v;                 // LeakyReLU(0.2)
          const float p = __expf(v - 40.f);           // fixed-shift numerator
          ls[mf * 4 + r] += p;
          Pl[w][base + r * 8] = f2bf(p);
        }
      }
    }

    // swapped PV: out^T[d][q] += A(V^T) x B(P^T via BT=[q][kv])
#pragma unroll
    for (int ks = 0; ks < 2; ++ks){
      short8 va[4], pf[4];
#pragma unroll
      for (int f = 0; f < 4; ++f){
        va[f] = *(const short8*)&Vt[((ks * 4 + lq) * 64 + f * 16 + l15) * 8];
        pf[f] = *(const short8*)&Pl[w][((ks * 4 + lq) * 64 + f * 16 + l15) * 8];
      }
#pragma unroll
      for (int df = 0; df < 4; ++df)
#pragma unroll
        for (int qf = 0; qf < 4; ++qf)
          o_[df][qf] = mfma16(va[df], pf[qf], o_[df][qf]);
    }
    __syncthreads();
  }

  // row-sum reduce across l15 groups, redistribute via LDS
#pragma unroll
  for (int mask = 1; mask < 16; mask <<= 1)
#pragma unroll
    for (int i = 0; i < 16; ++i)
      ls[i] += __shfl_xor(ls[i], mask, 64);
  if (l15 == 0){
#pragma unroll
    for (int mf = 0; mf < 4; ++mf)
#pragma unroll
      for (int r = 0; r < 4; ++r)
        Ls[w][mf * 16 + lq * 4 + r] = ls[mf * 4 + r];
  }
  __syncthreads();
  float inv[4];
#pragma unroll
  for (int qf = 0; qf < 4; ++qf) inv[qf] = 1.0f / Ls[w][qf * 16 + l15];

#pragma unroll
  for (int qf = 0; qf < 4; ++qf)
#pragma unroll
    for (int df = 0; df < 4; ++df){
      const size_t addr = (qrow0 + qf * 16 + l15) * 256 + h * 64 + df * 16 + lq * 4;
      st4bf(ao + addr,
            f2bf(o_[df][qf][0] * inv[qf]), f2bf(o_[df][qf][1] * inv[qf]),
            f2bf(o_[df][qf][2] * inv[qf]), f2bf(o_[df][qf][3] * inv[qf]));
    }
}

// ---------------------------------------------------------------- BN helpers
__global__ __launch_bounds__(256) void bn_partial(const float* __restrict__ buf,
                                                  float* __restrict__ part)
{
  const int bi = blockIdx.x, t = threadIdx.x;
  const float* p = buf + (size_t)bi * 64 * 256 + t;
  float s = 0.f, q = 0.f;
#pragma unroll 4
  for (int r = 0; r < 64; ++r){ const float v = p[(size_t)r * 256]; s += v; q = fmaf(v, v, q); }
  part[bi * 512 + t] = s;
  part[bi * 512 + 256 + t] = q;
}

__global__ __launch_bounds__(256) void bn_final(const float* __restrict__ part,
                                                const float* __restrict__ gamma,
                                                const float* __restrict__ beta,
                                                float* __restrict__ prm)
{
  const int t = threadIdx.x;
  float s = 0.f, q = 0.f;
#pragma unroll 8
  for (int i = 0; i < 256; ++i){ s += part[i * 512 + t]; q += part[i * 512 + 256 + t]; }
  const float mu = s * (1.f / 16384.f);
  const float var = q * (1.f / 16384.f) - mu * mu;
  prm[t] = mu;
  prm[256 + t] = rsqrtf(var + 1e-5f) * gamma[t];
  prm[512 + t] = beta[t];
}

// BN1 apply + relu + split to bf16 hi/lo
__global__ __launch_bounds__(256) void bn_apply_split(const float* __restrict__ in,
    u16* __restrict__ H, u16* __restrict__ L, const float* __restrict__ prm)
{
  const int idx = blockIdx.x * 256 + threadIdx.x;
  const size_t off = (size_t)idx * 4;
  const int o = (int)(off & 255);
  const float4 x = ld4(in + off);
  const float4 m = ld4(prm + o), rs = ld4(prm + 256 + o), bt = ld4(prm + 512 + o);
  u16 h_[4], l_[4];
  float v;
  v = fmaxf(fmaf(x.x - m.x, rs.x, bt.x), 0.f); h_[0] = f2bf(v); l_[0] = f2bf(v - bf2f(h_[0]));
  v = fmaxf(fmaf(x.y - m.y, rs.y, bt.y), 0.f); h_[1] = f2bf(v); l_[1] = f2bf(v - bf2f(h_[1]));
  v = fmaxf(fmaf(x.z - m.z, rs.z, bt.z), 0.f); h_[2] = f2bf(v); l_[2] = f2bf(v - bf2f(h_[2]));
  v = fmaxf(fmaf(x.w - m.w, rs.w, bt.w), 0.f); h_[3] = f2bf(v); l_[3] = f2bf(v - bf2f(h_[3]));
  st4bf(H + off, h_[0], h_[1], h_[2], h_[3]);
  st4bf(L + off, l_[0], l_[1], l_[2], l_[3]);
}

// BN2 apply + relu, fp32 in-place
__global__ __launch_bounds__(256) void bn_apply(const float* __restrict__ in,
                                                float* __restrict__ outp,
                                                const float* __restrict__ prm)
{
  const int idx = blockIdx.x * 256 + threadIdx.x;
  const size_t off = (size_t)idx * 8;
  const int o = (int)(off & 255);
  const float4 x0 = ld4(in + off),      x1 = ld4(in + off + 4);
  const float4 m0 = ld4(prm + o),       m1 = ld4(prm + o + 4);
  const float4 r0 = ld4(prm + 256 + o), r1 = ld4(prm + 256 + o + 4);
  const float4 b0 = ld4(prm + 512 + o), b1 = ld4(prm + 512 + o + 4);
  float4 y0, y1;
  y0.x = fmaxf(fmaf(x0.x - m0.x, r0.x, b0.x), 0.f);
  y0.y = fmaxf(fmaf(x0.y - m0.y, r0.y, b0.y), 0.f);
  y0.z = fmaxf(fmaf(x0.z - m0.z, r0.z, b0.z), 0.f);
  y0.w = fmaxf(fmaf(x0.w - m0.w, r0.w, b0.w), 0.f);
  y1.x = fmaxf(fmaf(x1.x - m1.x, r1.x, b1.x), 0.f);
  y1.y = fmaxf(fmaf(x1.y - m1.y, r1.y, b1.y), 0.f);
  y1.z = fmaxf(fmaf(x1.z - m1.z, r1.z, b1.z), 0.f);
  y1.w = fmaxf(fmaf(x1.w - m1.w, r1.w, b1.w), 0.f);
  st4(outp + off, y0);
  st4(outp + off + 4, y1);
}

// ---------------------------------------------------------------- pack / convert
// x->bf16; adj->hi/lo; gc_w->w0t[o][f]; gat_w->w2t hi/lo [c][f]; conv_w->cwt[co][kz*256+ci]; zbuf=0
__global__ __launch_bounds__(256) void pack_w(
    const float* __restrict__ x, const float* __restrict__ adj,
    const float* __restrict__ gcw, const float* __restrict__ gatw,
    const float* __restrict__ convw,
    u16* __restrict__ xbf, u16* __restrict__ adjh, u16* __restrict__ adjl,
    u16* __restrict__ w0t, u16* __restrict__ w2th, u16* __restrict__ w2tl,
    u16* __restrict__ cwt, u16* __restrict__ zb)
{
  const int idx = blockIdx.x * 256 + threadIdx.x;
  if (idx < 2097152) xbf[idx] = f2bf(x[idx]);
  if (idx < 1048576){
    const float v = adj[idx];
    const u16 hi = f2bf(v);
    adjh[idx] = hi; adjl[idx] = f2bf(v - bf2f(hi));
  }
  if (idx < 32768){
    const int o = idx >> 7, f = idx & 127;
    w0t[idx] = f2bf(gcw[f * 256 + o]);
  }
  if (idx < 65536){
    const int c = idx >> 8, f = idx & 255;
    const float v = gatw[(c >> 6) * 16384 + f * 64 + (c & 63)];
    const u16 hi = f2bf(v);
    w2th[idx] = hi; w2tl[idx] = f2bf(v - bf2f(hi));
  }
  if (idx < 196608){
    const int co = idx / 768, k = idx - co * 768;
    const int kz = k >> 8, ci = k & 255;
    cwt[idx] = f2bf(convw[co * 768 + ci * 3 + kz]);
  }
  if (idx < 2048) zb[idx] = 0;
}

// ---------------------------------------------------------------- launch
extern "C" void kernel_launch(void* const* d_in, const int* in_sizes, int n_in,
                              void* d_out, int out_size, void* d_ws, size_t ws_size,
                              hipStream_t stream)
{
  const float* x     = (const float*)d_in[0];
  const float* adj   = (const float*)d_in[1];
  const float* gc_w  = (const float*)d_in[2];
  const float* gc_b  = (const float*)d_in[3];
  const float* bn1g  = (const float*)d_in[4];
  const float* bn1b  = (const float*)d_in[5];
  const float* gatw  = (const float*)d_in[6];
  const float* convw = (const float*)d_in[7];
  const float* convb = (const float*)d_in[8];
  const float* bn2g  = (const float*)d_in[9];
  const float* bn2b  = (const float*)d_in[10];
  char* ws  = (char*)d_ws;
  char* out = (char*)d_out;

  // ws layout (bytes), total ~25.3 MB:
  u16* h1t_hi = (u16*)(ws + 0);              // 8 MB  [bo][node]   (later: h_hi, then ao)
  u16* h1t_lo = (u16*)(ws + 8388608);        // 8 MB               (later: h_lo)
  u16* x_bf   = (u16*)(ws + 16777216);       // 4 MB               (later: hpT 8MB @16M)
  u16* adj_hi = (u16*)(ws + 20971520);       // 2 MB
  u16* adj_lo = (u16*)(ws + 23068672);       // 2 MB
  u16* hpT    = (u16*)(ws + 16777216);       // 8 MB (aliases x_bf+adj; live after both die)
  u16* w0t    = (u16*)(ws + 25165824);       // 64 KB
  u16* w2th   = (u16*)(ws + 25231360);       // 128 KB
  u16* w2tl   = (u16*)(ws + 25362432);       // 128 KB
  u16* cwt    = (u16*)(ws + 25493504);       // 384 KB
  u16* zbuf   = (u16*)(ws + 25886720);       // 4 KB zeros
  float* P1   = (float*)(ws + 25890816);     // 512 KB bn partials
  float* PR1  = (float*)(ws + 26415104);     // 3 KB
  float* PR2  = (float*)(ws + 26419200);     // 3 KB
  // aliases into ws/out across phases:
  u16* h_hi  = (u16*)(ws + 0);
  u16* h_lo  = (u16*)(ws + 8388608);
  u16* ao    = (u16*)(ws + 0);
  float* g   = (float*)out;                  // gemm1 out (16 MB), dead after bn_apply_split
  u16* hp_hi = (u16*)out;                    // gemm2 out, dead after flash
  u16* hp_lo = (u16*)(out + 8388608);
  float* y   = (float*)out;                  // gemm3 out -> bn2 in-place -> final

  pack_w<<<8192, 256, 0, stream>>>(x, adj, gc_w, gatw, convw,
                                   x_bf, adj_hi, adj_lo, w0t, w2th, w2tl, cwt, zbuf);
  // gemm0: x_bf @ w0t -> h1t hi/lo
  gemm0_k<<<dim3(2, 128), 256, 0, stream>>>(x_bf, w0t, zbuf, h1t_hi, h1t_lo);
  // gemm1 (split): adj @ h1t -> g (+gc_b, relu)
  gemm1_k<<<dim3(32, 8), 256, 0, stream>>>(adj_hi, adj_lo, h1t_hi, h1t_lo, zbuf, g, gc_b);
  bn_partial<<<256, 256, 0, stream>>>(g, P1);
  bn_final<<<1, 256, 0, stream>>>(P1, bn1g, bn1b, PR1);
  bn_apply_split<<<4096, 256, 0, stream>>>(g, h_hi, h_lo, PR1);
  // gemm2 (split): h @ w2t -> hp hi/lo + hpT
  gemm2_k<<<dim3(2, 128), 256, 0, stream>>>(h_hi, h_lo, w2th, w2tl, zbuf, hp_hi, hp_lo, hpT);
  // flash GAT
  flash<<<256, 256, 0, stream>>>(hp_hi, hp_lo, hpT, ao);
  // gemm3: im2col(ao) @ cwt -> y (+conv_b)
  gemm3_k<<<dim3(2, 128), 256, 0, stream>>>(ao, cwt, zbuf, y, convb);
  bn_partial<<<256, 256, 0, stream>>>(y, P1);
  bn_final<<<1, 256, 0, stream>>>(P1, bn2g, bn2b, PR2);
  bn_apply<<<2048, 256, 0, stream>>>(y, y, PR2);
}

// Round 6
// 321.584 us; speedup vs baseline: 2.4143x; 1.0537x over previous
//
#include <hip/hip_runtime.h>
#include <hip/hip_bf16.h>

// GCN + MultiHead GAT + TCN — bf16 MFMA pipeline with split-precision paths.
// B=16, N=1024, NFEAT=128, NHID=256, NOUT=256, H=4, DH=64.
//
// Round 5 -> 6: flash was 1 block/CU (grid 256, Occupancy 10.3%, MfmaUtil 16%)
// -> restructure to 512 blocks x 128 q-rows (mf=2), LDS 40.5KB -> 2 blocks/CU
// -> 2 waves/SIMD so exp-VALU and LDS phases of one wave hide under MFMA of the
// other (m114 overlap). XCD-affinity bid mapping (xcd = bid%8 = b%8). gemm1
// grid axes swapped so each XCD owns one m-row (adj panel L2 reuse).
//
// Precision plan (BN1 amplifies pre-BN errors ~100x; exp amplifies e-errors):
//   gemm0 plain bf16; gemm1 SPLIT hi/lo both sides; gemm2 SPLIT; flash QK^T
//   SPLIT q,k; flash PV plain (P in [0,1], sum=1); gemm3 plain.
// MFMA: v_mfma_f32_16x16x32_bf16. A[row=l&15][k=(l>>4)*8+i], B likewise on BT
// storage, D[col=l&15][row=(l>>4)*4+reg] (m89-verified).
// LDS tiles [k/8][row][8] staged via global_load_lds(16B), per-lane permuted
// global source (m173), wave-uniform LDS base.

typedef unsigned short u16;
typedef __attribute__((ext_vector_type(8))) short short8;  // 8 bf16 = 4 VGPR
typedef __attribute__((ext_vector_type(4))) float f32x4;

static __device__ __forceinline__ float4 ld4(const float* p){ return *(const float4*)p; }
static __device__ __forceinline__ void st4(float* p, float4 v){ *(float4*)p = v; }

static __device__ __forceinline__ u16 f2bf(float f){           // RNE
  unsigned u = __builtin_bit_cast(unsigned, f);
  unsigned r = u + 0x7FFFu + ((u >> 16) & 1u);
  return (u16)(r >> 16);
}
static __device__ __forceinline__ float bf2f(u16 h){
  unsigned u = ((unsigned)h) << 16; return __builtin_bit_cast(float, u);
}
static __device__ __forceinline__ void st4bf(u16* p, u16 a, u16 b, u16 c, u16 d){
  uint2 v; v.x = (unsigned)a | ((unsigned)b << 16); v.y = (unsigned)c | ((unsigned)d << 16);
  *(uint2*)p = v;
}
static __device__ __forceinline__ f32x4 mfma16(short8 a, short8 b, f32x4 c){
  return __builtin_amdgcn_mfma_f32_16x16x32_bf16(a, b, c, 0, 0, 0);
}

// ---------------------------------------------------------------- MFMA GEMM body
// A [M][K] bf16 row-major (hi/lo), B as BT [NN][K] bf16 (hi/lo).
// AXSWAP: m on blockIdx.x (so flat%8 = m-row -> one m-row per XCD).
template<int SPLIT, int K, int NN, int MODE, int AXSWAP>
static __device__ __forceinline__ void mgemm_body(
    const u16* __restrict__ Ah_, const u16* __restrict__ Al_,
    const u16* __restrict__ Bh_, const u16* __restrict__ Bl_,
    const u16* __restrict__ zbuf,
    void* __restrict__ C0v, void* __restrict__ C1v, void* __restrict__ C2v,
    const float* __restrict__ bias)
{
  constexpr int KT = K / 32;
  __shared__ u16 Ah[4096], Bh[4096];
  __shared__ u16 Al[SPLIT == 3 ? 4096 : 8], Bl[SPLIT == 3 ? 4096 : 8];
  const int tid = threadIdx.x;
  const int n0 = (AXSWAP ? blockIdx.y : blockIdx.x) * 128;
  const int m0 = (AXSWAP ? blockIdx.x : blockIdx.y) * 128;
  const int lane = tid & 63, l15 = lane & 15, lq = lane >> 4;
  const int w = tid >> 6, wr = w >> 1, wc = w & 1;

  f32x4 acc[4][4] = {};

  for (int kt = 0; kt < KT; ++kt){
    const int k0 = kt * 32;
#pragma unroll
    for (int r = 0; r < 2; ++r){
      const int slot = r * 256 + tid;
      const int row = slot & 127, kh = slot >> 7;
      const int ldsoff = (r * 256 + (tid & 192)) * 8;   // wave-uniform base slot*8
      const u16* asrc;
      if constexpr (MODE == 3){
        const int kz = k0 >> 8;
        const int ci0 = (k0 & 255) + kh * 8;
        const int R = m0 + row;
        const int nn = (R & 1023) + kz - 1;
        asrc = ((unsigned)nn < 1024u) ? (Ah_ + (size_t)(R + kz - 1) * 256 + ci0) : zbuf;
      } else {
        asrc = Ah_ + (size_t)(m0 + row) * K + k0 + kh * 8;
      }
      __builtin_amdgcn_global_load_lds(asrc, &Ah[ldsoff], 16, 0, 0);
      const u16* bsrc = Bh_ + (size_t)(n0 + row) * K + k0 + kh * 8;
      __builtin_amdgcn_global_load_lds(bsrc, &Bh[ldsoff], 16, 0, 0);
      if constexpr (SPLIT == 3){
        const u16* asrc2 = Al_ + (size_t)(m0 + row) * K + k0 + kh * 8;
        __builtin_amdgcn_global_load_lds(asrc2, &Al[ldsoff], 16, 0, 0);
        const u16* bsrc2 = Bl_ + (size_t)(n0 + row) * K + k0 + kh * 8;
        __builtin_amdgcn_global_load_lds(bsrc2, &Bl[ldsoff], 16, 0, 0);
      }
    }
    __syncthreads();
    short8 afh[4], bfh[4], afl[4], bfl[4];
#pragma unroll
    for (int f = 0; f < 4; ++f){
      afh[f] = *(const short8*)&Ah[(lq * 128 + wr * 64 + f * 16 + l15) * 8];
      bfh[f] = *(const short8*)&Bh[(lq * 128 + wc * 64 + f * 16 + l15) * 8];
      if constexpr (SPLIT == 3){
        afl[f] = *(const short8*)&Al[(lq * 128 + wr * 64 + f * 16 + l15) * 8];
        bfl[f] = *(const short8*)&Bl[(lq * 128 + wc * 64 + f * 16 + l15) * 8];
      }
    }
#pragma unroll
    for (int fi = 0; fi < 4; ++fi)
#pragma unroll
      for (int fj = 0; fj < 4; ++fj){
        acc[fi][fj] = mfma16(afh[fi], bfh[fj], acc[fi][fj]);
        if constexpr (SPLIT == 3){
          acc[fi][fj] = mfma16(afl[fi], bfh[fj], acc[fi][fj]);
          acc[fi][fj] = mfma16(afh[fi], bfl[fj], acc[fi][fj]);
        }
      }
    __syncthreads();
  }

  const int rb = m0 + wr * 64;
  const int cb = n0 + wc * 64;
  if constexpr (MODE == 0){
    u16* H = (u16*)C0v; u16* L = (u16*)C1v;
#pragma unroll
    for (int fi = 0; fi < 4; ++fi){
      const int R = rb + fi * 16 + lq * 4;
      const int nn = R & 1023, bq = R >> 10;
#pragma unroll
      for (int fj = 0; fj < 4; ++fj){
        const int c = cb + fj * 16 + l15;
        const size_t off = (size_t)(bq * 256 + c) * 1024 + nn;
        u16 h_[4], l_[4];
#pragma unroll
        for (int r = 0; r < 4; ++r){
          float v = acc[fi][fj][r];
          u16 hi = f2bf(v); h_[r] = hi; l_[r] = f2bf(v - bf2f(hi));
        }
        st4bf(H + off, h_[0], h_[1], h_[2], h_[3]);
        st4bf(L + off, l_[0], l_[1], l_[2], l_[3]);
      }
    }
  } else if constexpr (MODE == 1){
    float* G = (float*)C0v;
#pragma unroll
    for (int fj = 0; fj < 4; ++fj){
      const int c = cb + fj * 16 + l15;          // bo
      const int o = c & 255, bq = c >> 8;
      const float bs = bias[o];
#pragma unroll
      for (int fi = 0; fi < 4; ++fi){
        const int R = rb + fi * 16 + lq * 4;     // node n
#pragma unroll
        for (int r = 0; r < 4; ++r)
          G[((size_t)bq * 1024 + R + r) * 256 + o] = fmaxf(acc[fi][fj][r] + bs, 0.f);
      }
    }
  } else if constexpr (MODE == 2){
    u16* H = (u16*)C0v; u16* L = (u16*)C1v; u16* T = (u16*)C2v;
#pragma unroll
    for (int fi = 0; fi < 4; ++fi){
      const int R = rb + fi * 16 + lq * 4;
#pragma unroll
      for (int fj = 0; fj < 4; ++fj){
        const int c = cb + fj * 16 + l15;
        u16 h_[4];
#pragma unroll
        for (int r = 0; r < 4; ++r){
          float v = acc[fi][fj][r];
          u16 hi = f2bf(v); h_[r] = hi;
          H[(size_t)(R + r) * 256 + c] = hi;
          L[(size_t)(R + r) * 256 + c] = f2bf(v - bf2f(hi));
        }
        st4bf(T + (size_t)c * 16384 + R, h_[0], h_[1], h_[2], h_[3]);
      }
    }
  } else {
    float* Y = (float*)C0v;
#pragma unroll
    for (int fj = 0; fj < 4; ++fj){
      const int c = cb + fj * 16 + l15;
      const float bs = bias[c];
#pragma unroll
      for (int fi = 0; fi < 4; ++fi){
        const int R = rb + fi * 16 + lq * 4;
#pragma unroll
        for (int r = 0; r < 4; ++r)
          Y[(size_t)(R + r) * 256 + c] = acc[fi][fj][r] + bs;
      }
    }
  }
}

// Non-template wrappers (hipcc drops stubs for template __global__ in .so).
__global__ __launch_bounds__(256) void gemm0_k(
    const u16* __restrict__ Ah_, const u16* __restrict__ Bh_,
    const u16* __restrict__ zbuf, void* __restrict__ C0, void* __restrict__ C1)
{ mgemm_body<1, 128, 256, 0, 0>(Ah_, nullptr, Bh_, nullptr, zbuf, C0, C1, nullptr, nullptr); }

__global__ __launch_bounds__(256) void gemm1_k(
    const u16* __restrict__ Ah_, const u16* __restrict__ Al_,
    const u16* __restrict__ Bh_, const u16* __restrict__ Bl_,
    const u16* __restrict__ zbuf, void* __restrict__ C0, const float* __restrict__ bias)
{ mgemm_body<3, 1024, 4096, 1, 1>(Ah_, Al_, Bh_, Bl_, zbuf, C0, nullptr, nullptr, bias); }

__global__ __launch_bounds__(256) void gemm2_k(
    const u16* __restrict__ Ah_, const u16* __restrict__ Al_,
    const u16* __restrict__ Bh_, const u16* __restrict__ Bl_,
    const u16* __restrict__ zbuf,
    void* __restrict__ C0, void* __restrict__ C1, void* __restrict__ C2)
{ mgemm_body<3, 256, 256, 2, 0>(Ah_, Al_, Bh_, Bl_, zbuf, C0, C1, C2, nullptr); }

__global__ __launch_bounds__(256) void gemm3_k(
    const u16* __restrict__ Ah_, const u16* __restrict__ Bh_,
    const u16* __restrict__ zbuf, void* __restrict__ C0, const float* __restrict__ bias)
{ mgemm_body<1, 768, 256, 3, 0>(Ah_, nullptr, Bh_, nullptr, zbuf, C0, nullptr, nullptr, bias); }

// ---------------------------------------------------------------- flash GAT (MFMA)
// Grid 512: bid -> b = bid&15 (xcd = bid%8 = b%8: 2 b's worth of K/V per XCD L2),
// k = bid>>4, h = k>>3, qo = k&7. Block = 128 q-rows, 4 waves x 32 rows (mf=2).
// Per 64-kv tile: stage K hi/lo [dk][kv][8] + V^T [kk][d][8]; QK^T split (6 MFMA/cell);
// p = exp(s-40) (exact: e <= max||hp||^2 ~50 by Cauchy-Schwarz, diag >= 0 keeps
// the sum >= exp(-40)); P per-wave LDS [kk][q32][8]; swapped PV out^T = Vt x P.
__global__ __launch_bounds__(256) void flash(
    const u16* __restrict__ hp_hi, const u16* __restrict__ hp_lo,
    const u16* __restrict__ hpT, u16* __restrict__ ao)
{
  __shared__ u16 Khi[4096], Klo[4096], Vt[4096];
  __shared__ u16 Pl[4][2048];
  __shared__ float Ls[4][32];
  const int tid = threadIdx.x;
  const int lane = tid & 63, l15 = lane & 15, lq = lane >> 4, w = tid >> 6;
  const int bid = blockIdx.x;
  const int b = bid & 15, k_ = bid >> 4, h = k_ >> 3, qo = k_ & 7;
  const size_t qrow0 = (size_t)b * 1024 + qo * 128 + w * 32;

  short8 qh[2][2], ql[2][2];
#pragma unroll
  for (int mf = 0; mf < 2; ++mf)
#pragma unroll
    for (int ks = 0; ks < 2; ++ks){
      const size_t off = (qrow0 + mf * 16 + l15) * 256 + h * 64 + ks * 32 + lq * 8;
      qh[mf][ks] = *(const short8*)(hp_hi + off);
      ql[mf][ks] = *(const short8*)(hp_lo + off);
    }

  f32x4 o_[4][2] = {};   // out^T acc: [df][qf]
  float ls[8] = {};      // row-sum partials: [mf*4+r]

  for (int kt = 0; kt < 16; ++kt){
    const int kv0 = kt * 64;
#pragma unroll
    for (int r = 0; r < 2; ++r){
      const int slot = r * 256 + tid;
      const int g1 = slot >> 6, g2 = slot & 63;     // [g1][g2] of 8x64
      const int ldsoff = (r * 256 + (tid & 192)) * 8;
      const u16* ksrc = hp_hi + ((size_t)b * 1024 + kv0 + g2) * 256 + h * 64 + g1 * 8;
      __builtin_amdgcn_global_load_lds(ksrc, &Khi[ldsoff], 16, 0, 0);
      const u16* ksrc2 = hp_lo + ((size_t)b * 1024 + kv0 + g2) * 256 + h * 64 + g1 * 8;
      __builtin_amdgcn_global_load_lds(ksrc2, &Klo[ldsoff], 16, 0, 0);
      const u16* vsrc = hpT + (size_t)(h * 64 + g2) * 16384 + b * 1024 + kv0 + g1 * 8;
      __builtin_amdgcn_global_load_lds(vsrc, &Vt[ldsoff], 16, 0, 0);
    }
    __syncthreads();

    // QK^T + softmax numerator + P write
#pragma unroll
    for (int nf = 0; nf < 4; ++nf){
      short8 kf[2], kg[2];
#pragma unroll
      for (int ks = 0; ks < 2; ++ks){
        kf[ks] = *(const short8*)&Khi[((ks * 4 + lq) * 64 + nf * 16 + l15) * 8];
        kg[ks] = *(const short8*)&Klo[((ks * 4 + lq) * 64 + nf * 16 + l15) * 8];
      }
      const int kv = nf * 16 + l15;
#pragma unroll
      for (int mf = 0; mf < 2; ++mf){
        f32x4 s = {};
#pragma unroll
        for (int ks = 0; ks < 2; ++ks){
          s = mfma16(qh[mf][ks], kf[ks], s);
          s = mfma16(ql[mf][ks], kf[ks], s);
          s = mfma16(qh[mf][ks], kg[ks], s);
        }
        const int qb = mf * 16 + lq * 4;
        const int base = ((kv >> 3) * 32 + qb) * 8 + (kv & 7);
#pragma unroll
        for (int r = 0; r < 4; ++r){
          float v = s[r];
          v = v > 0.f ? v : 0.2f * v;                 // LeakyReLU(0.2)
          const float p = __expf(v - 40.f);           // fixed-shift numerator
          ls[mf * 4 + r] += p;
          Pl[w][base + r * 8] = f2bf(p);
        }
      }
    }

    // swapped PV: out^T[d][q] += A(V^T) x B(P as BT [q32][kv])
#pragma unroll
    for (int ks = 0; ks < 2; ++ks){
      short8 va[4], pf[2];
#pragma unroll
      for (int f = 0; f < 4; ++f)
        va[f] = *(const short8*)&Vt[((ks * 4 + lq) * 64 + f * 16 + l15) * 8];
#pragma unroll
      for (int f = 0; f < 2; ++f)
        pf[f] = *(const short8*)&Pl[w][((ks * 4 + lq) * 32 + f * 16 + l15) * 8];
#pragma unroll
      for (int df = 0; df < 4; ++df)
#pragma unroll
        for (int qf = 0; qf < 2; ++qf)
          o_[df][qf] = mfma16(va[df], pf[qf], o_[df][qf]);
    }
    __syncthreads();
  }

  // row-sum reduce across l15 groups, redistribute via LDS
#pragma unroll
  for (int mask = 1; mask < 16; mask <<= 1)
#pragma unroll
    for (int i = 0; i < 8; ++i)
      ls[i] += __shfl_xor(ls[i], mask, 64);
  if (l15 == 0){
#pragma unroll
    for (int mf = 0; mf < 2; ++mf)
#pragma unroll
      for (int r = 0; r < 4; ++r)
        Ls[w][mf * 16 + lq * 4 + r] = ls[mf * 4 + r];
  }
  __syncthreads();
  float inv[2];
#pragma unroll
  for (int qf = 0; qf < 2; ++qf) inv[qf] = 1.0f / Ls[w][qf * 16 + l15];

#pragma unroll
  for (int qf = 0; qf < 2; ++qf)
#pragma unroll
    for (int df = 0; df < 4; ++df){
      const size_t addr = (qrow0 + qf * 16 + l15) * 256 + h * 64 + df * 16 + lq * 4;
      st4bf(ao + addr,
            f2bf(o_[df][qf][0] * inv[qf]), f2bf(o_[df][qf][1] * inv[qf]),
            f2bf(o_[df][qf][2] * inv[qf]), f2bf(o_[df][qf][3] * inv[qf]));
    }
}

// ---------------------------------------------------------------- BN helpers
__global__ __launch_bounds__(256) void bn_partial(const float* __restrict__ buf,
                                                  float* __restrict__ part)
{
  const int bi = blockIdx.x, t = threadIdx.x;
  const float* p = buf + (size_t)bi * 64 * 256 + t;
  float s = 0.f, q = 0.f;
#pragma unroll 4
  for (int r = 0; r < 64; ++r){ const float v = p[(size_t)r * 256]; s += v; q = fmaf(v, v, q); }
  part[bi * 512 + t] = s;
  part[bi * 512 + 256 + t] = q;
}

__global__ __launch_bounds__(256) void bn_final(const float* __restrict__ part,
                                                const float* __restrict__ gamma,
                                                const float* __restrict__ beta,
                                                float* __restrict__ prm)
{
  const int t = threadIdx.x;
  float s = 0.f, q = 0.f;
#pragma unroll 8
  for (int i = 0; i < 256; ++i){ s += part[i * 512 + t]; q += part[i * 512 + 256 + t]; }
  const float mu = s * (1.f / 16384.f);
  const float var = q * (1.f / 16384.f) - mu * mu;
  prm[t] = mu;
  prm[256 + t] = rsqrtf(var + 1e-5f) * gamma[t];
  prm[512 + t] = beta[t];
}

// BN1 apply + relu + split to bf16 hi/lo
__global__ __launch_bounds__(256) void bn_apply_split(const float* __restrict__ in,
    u16* __restrict__ H, u16* __restrict__ L, const float* __restrict__ prm)
{
  const int idx = blockIdx.x * 256 + threadIdx.x;
  const size_t off = (size_t)idx * 4;
  const int o = (int)(off & 255);
  const float4 x = ld4(in + off);
  const float4 m = ld4(prm + o), rs = ld4(prm + 256 + o), bt = ld4(prm + 512 + o);
  u16 h_[4], l_[4];
  float v;
  v = fmaxf(fmaf(x.x - m.x, rs.x, bt.x), 0.f); h_[0] = f2bf(v); l_[0] = f2bf(v - bf2f(h_[0]));
  v = fmaxf(fmaf(x.y - m.y, rs.y, bt.y), 0.f); h_[1] = f2bf(v); l_[1] = f2bf(v - bf2f(h_[1]));
  v = fmaxf(fmaf(x.z - m.z, rs.z, bt.z), 0.f); h_[2] = f2bf(v); l_[2] = f2bf(v - bf2f(h_[2]));
  v = fmaxf(fmaf(x.w - m.w, rs.w, bt.w), 0.f); h_[3] = f2bf(v); l_[3] = f2bf(v - bf2f(h_[3]));
  st4bf(H + off, h_[0], h_[1], h_[2], h_[3]);
  st4bf(L + off, l_[0], l_[1], l_[2], l_[3]);
}

// BN2 apply + relu, fp32 in-place
__global__ __launch_bounds__(256) void bn_apply(const float* __restrict__ in,
                                                float* __restrict__ outp,
                                                const float* __restrict__ prm)
{
  const int idx = blockIdx.x * 256 + threadIdx.x;
  const size_t off = (size_t)idx * 8;
  const int o = (int)(off & 255);
  const float4 x0 = ld4(in + off),      x1 = ld4(in + off + 4);
  const float4 m0 = ld4(prm + o),       m1 = ld4(prm + o + 4);
  const float4 r0 = ld4(prm + 256 + o), r1 = ld4(prm + 256 + o + 4);
  const float4 b0 = ld4(prm + 512 + o), b1 = ld4(prm + 512 + o + 4);
  float4 y0, y1;
  y0.x = fmaxf(fmaf(x0.x - m0.x, r0.x, b0.x), 0.f);
  y0.y = fmaxf(fmaf(x0.y - m0.y, r0.y, b0.y), 0.f);
  y0.z = fmaxf(fmaf(x0.z - m0.z, r0.z, b0.z), 0.f);
  y0.w = fmaxf(fmaf(x0.w - m0.w, r0.w, b0.w), 0.f);
  y1.x = fmaxf(fmaf(x1.x - m1.x, r1.x, b1.x), 0.f);
  y1.y = fmaxf(fmaf(x1.y - m1.y, r1.y, b1.y), 0.f);
  y1.z = fmaxf(fmaf(x1.z - m1.z, r1.z, b1.z), 0.f);
  y1.w = fmaxf(fmaf(x1.w - m1.w, r1.w, b1.w), 0.f);
  st4(outp + off, y0);
  st4(outp + off + 4, y1);
}

// ---------------------------------------------------------------- pack / convert
__global__ __launch_bounds__(256) void pack_w(
    const float* __restrict__ x, const float* __restrict__ adj,
    const float* __restrict__ gcw, const float* __restrict__ gatw,
    const float* __restrict__ convw,
    u16* __restrict__ xbf, u16* __restrict__ adjh, u16* __restrict__ adjl,
    u16* __restrict__ w0t, u16* __restrict__ w2th, u16* __restrict__ w2tl,
    u16* __restrict__ cwt, u16* __restrict__ zb)
{
  const int idx = blockIdx.x * 256 + threadIdx.x;
  if (idx < 2097152) xbf[idx] = f2bf(x[idx]);
  if (idx < 1048576){
    const float v = adj[idx];
    const u16 hi = f2bf(v);
    adjh[idx] = hi; adjl[idx] = f2bf(v - bf2f(hi));
  }
  if (idx < 32768){
    const int o = idx >> 7, f = idx & 127;
    w0t[idx] = f2bf(gcw[f * 256 + o]);
  }
  if (idx < 65536){
    const int c = idx >> 8, f = idx & 255;
    const float v = gatw[(c >> 6) * 16384 + f * 64 + (c & 63)];
    const u16 hi = f2bf(v);
    w2th[idx] = hi; w2tl[idx] = f2bf(v - bf2f(hi));
  }
  if (idx < 196608){
    const int co = idx / 768, k = idx - co * 768;
    const int kz = k >> 8, ci = k & 255;
    cwt[idx] = f2bf(convw[co * 768 + ci * 3 + kz]);
  }
  if (idx < 2048) zb[idx] = 0;
}

// ---------------------------------------------------------------- launch
extern "C" void kernel_launch(void* const* d_in, const int* in_sizes, int n_in,
                              void* d_out, int out_size, void* d_ws, size_t ws_size,
                              hipStream_t stream)
{
  const float* x     = (const float*)d_in[0];
  const float* adj   = (const float*)d_in[1];
  const float* gc_w  = (const float*)d_in[2];
  const float* gc_b  = (const float*)d_in[3];
  const float* bn1g  = (const float*)d_in[4];
  const float* bn1b  = (const float*)d_in[5];
  const float* gatw  = (const float*)d_in[6];
  const float* convw = (const float*)d_in[7];
  const float* convb = (const float*)d_in[8];
  const float* bn2g  = (const float*)d_in[9];
  const float* bn2b  = (const float*)d_in[10];
  char* ws  = (char*)d_ws;
  char* out = (char*)d_out;

  // ws layout (bytes), total ~25.3 MB:
  u16* h1t_hi = (u16*)(ws + 0);              // 8 MB  [bo][node]   (later: h_hi, then ao)
  u16* h1t_lo = (u16*)(ws + 8388608);        // 8 MB               (later: h_lo)
  u16* x_bf   = (u16*)(ws + 16777216);       // 4 MB               (later: hpT 8MB @16M)
  u16* adj_hi = (u16*)(ws + 20971520);       // 2 MB
  u16* adj_lo = (u16*)(ws + 23068672);       // 2 MB
  u16* hpT    = (u16*)(ws + 16777216);       // 8 MB (aliases x_bf+adj; live after both die)
  u16* w0t    = (u16*)(ws + 25165824);       // 64 KB
  u16* w2th   = (u16*)(ws + 25231360);       // 128 KB
  u16* w2tl   = (u16*)(ws + 25362432);       // 128 KB
  u16* cwt    = (u16*)(ws + 25493504);       // 384 KB
  u16* zbuf   = (u16*)(ws + 25886720);       // 4 KB zeros
  float* P1   = (float*)(ws + 25890816);     // 512 KB bn partials
  float* PR1  = (float*)(ws + 26415104);     // 3 KB
  float* PR2  = (float*)(ws + 26419200);     // 3 KB
  // aliases into ws/out across phases:
  u16* h_hi  = (u16*)(ws + 0);
  u16* h_lo  = (u16*)(ws + 8388608);
  u16* ao    = (u16*)(ws + 0);
  float* g   = (float*)out;                  // gemm1 out (16 MB), dead after bn_apply_split
  u16* hp_hi = (u16*)out;                    // gemm2 out, dead after flash
  u16* hp_lo = (u16*)(out + 8388608);
  float* y   = (float*)out;                  // gemm3 out -> bn2 in-place -> final

  pack_w<<<8192, 256, 0, stream>>>(x, adj, gc_w, gatw, convw,
                                   x_bf, adj_hi, adj_lo, w0t, w2th, w2tl, cwt, zbuf);
  // gemm0: x_bf @ w0t -> h1t hi/lo
  gemm0_k<<<dim3(2, 128), 256, 0, stream>>>(x_bf, w0t, zbuf, h1t_hi, h1t_lo);
  // gemm1 (split): adj @ h1t -> g (+gc_b, relu). m on x: one m-row per XCD.
  gemm1_k<<<dim3(8, 32), 256, 0, stream>>>(adj_hi, adj_lo, h1t_hi, h1t_lo, zbuf, g, gc_b);
  bn_partial<<<256, 256, 0, stream>>>(g, P1);
  bn_final<<<1, 256, 0, stream>>>(P1, bn1g, bn1b, PR1);
  bn_apply_split<<<4096, 256, 0, stream>>>(g, h_hi, h_lo, PR1);
  // gemm2 (split): h @ w2t -> hp hi/lo + hpT
  gemm2_k<<<dim3(2, 128), 256, 0, stream>>>(h_hi, h_lo, w2th, w2tl, zbuf, hp_hi, hp_lo, hpT);
  // flash GAT (512 blocks, 2/CU)
  flash<<<512, 256, 0, stream>>>(hp_hi, hp_lo, hpT, ao);
  // gemm3: im2col(ao) @ cwt -> y (+conv_b)
  gemm3_k<<<dim3(2, 128), 256, 0, stream>>>(ao, cwt, zbuf, y, convb);
  bn_partial<<<256, 256, 0, stream>>>(y, P1);
  bn_final<<<1, 256, 0, stream>>>(P1, bn2g, bn2b, PR2);
  bn_apply<<<2048, 256, 0, stream>>>(y, y, PR2);
}

// Round 7
// 314.698 us; speedup vs baseline: 2.4671x; 1.0219x over previous
//
#include <hip/hip_runtime.h>
#include <hip/hip_bf16.h>

// GCN + MultiHead GAT + TCN — bf16 MFMA pipeline with split-precision paths.
// B=16, N=1024, NFEAT=128, NHID=256, NOUT=256, H=4, DH=64.
//
// Round 6 -> 7: ALL mgemm grids were 256 blocks = 1 block/CU (gemm1: Occ 10%,
// MfmaUtil 14%) — same latency-bound disease flash had. Fix: halve one tile dim
// -> 512-block grids (2/CU): gemm1 64x128, gemm0/2/3 128x64. Wave frag shape
// (MI=4,NJ=2) is unchanged in all cases. Flash: 1024 blocks x 64 q-rows,
// LDS 32.3KB -> 4 blocks/CU.
//
// Precision plan: gemm0 plain bf16; gemm1 SPLIT hi/lo both sides (BN1
// amplifies pre-BN error ~100x); gemm2 SPLIT; flash QK^T SPLIT; flash PV
// plain (P in [0,1], sum=1); gemm3 plain.
// MFMA: v_mfma_f32_16x16x32_bf16. A[row=l&15][k=(l>>4)*8+i], B likewise on BT
// storage, D[col=l&15][row=(l>>4)*4+reg] (m89-verified).
// LDS tiles [k/8][row][8] staged via global_load_lds(16B), per-lane permuted
// global source (m173), wave-uniform LDS base.

typedef unsigned short u16;
typedef __attribute__((ext_vector_type(8))) short short8;  // 8 bf16 = 4 VGPR
typedef __attribute__((ext_vector_type(4))) float f32x4;

static __device__ __forceinline__ float4 ld4(const float* p){ return *(const float4*)p; }
static __device__ __forceinline__ void st4(float* p, float4 v){ *(float4*)p = v; }

static __device__ __forceinline__ u16 f2bf(float f){           // RNE
  unsigned u = __builtin_bit_cast(unsigned, f);
  unsigned r = u + 0x7FFFu + ((u >> 16) & 1u);
  return (u16)(r >> 16);
}
static __device__ __forceinline__ float bf2f(u16 h){
  unsigned u = ((unsigned)h) << 16; return __builtin_bit_cast(float, u);
}
static __device__ __forceinline__ void st4bf(u16* p, u16 a, u16 b, u16 c, u16 d){
  uint2 v; v.x = (unsigned)a | ((unsigned)b << 16); v.y = (unsigned)c | ((unsigned)d << 16);
  *(uint2*)p = v;
}
static __device__ __forceinline__ f32x4 mfma16(short8 a, short8 b, f32x4 c){
  return __builtin_amdgcn_mfma_f32_16x16x32_bf16(a, b, c, 0, 0, 0);
}

// ---------------------------------------------------------------- MFMA GEMM body
// A [M][K] bf16 row-major (hi/lo), B as BT [NN][K] bf16 (hi/lo).
// Tile BM x BN, 4 waves as WR x WC grid; wave tile (BM/WR)x(BN/WC).
// AXSWAP: m on blockIdx.x (XCD owns adj m-panels for gemm1).
template<int SPLIT, int K, int NN, int MODE, int AXSWAP, int BM, int BN, int WR, int WC>
static __device__ __forceinline__ void mgemm_body(
    const u16* __restrict__ Ah_, const u16* __restrict__ Al_,
    const u16* __restrict__ Bh_, const u16* __restrict__ Bl_,
    const u16* __restrict__ zbuf,
    void* __restrict__ C0v, void* __restrict__ C1v, void* __restrict__ C2v,
    const float* __restrict__ bias)
{
  constexpr int KT = K / 32;
  constexpr int WM = BM / WR, WN = BN / WC;
  constexpr int MI = WM / 16, NJ = WN / 16;
  __shared__ u16 Ah[BM * 32], Bh[BN * 32];
  __shared__ u16 Al[SPLIT == 3 ? BM * 32 : 8], Bl[SPLIT == 3 ? BN * 32 : 8];
  const int tid = threadIdx.x;
  const int n0 = (AXSWAP ? blockIdx.y : blockIdx.x) * BN;
  const int m0 = (AXSWAP ? blockIdx.x : blockIdx.y) * BM;
  const int lane = tid & 63, l15 = lane & 15, lq = lane >> 4;
  const int w = tid >> 6, wr = w / WC, wc = w % WC;

  f32x4 acc[MI][NJ] = {};

  for (int kt = 0; kt < KT; ++kt){
    const int k0 = kt * 32;
    // ---- stage A (BM/64 rounds of 4KB) ----
#pragma unroll
    for (int r = 0; r < BM / 64; ++r){
      const int slot = r * 256 + tid;
      const int row = slot & (BM - 1), kh = slot / BM;
      const int ldsoff = (r * 256 + (tid & 192)) * 8;   // wave-uniform; lane adds 16B
      const u16* asrc;
      if constexpr (MODE == 3){
        const int kz = k0 >> 8;
        const int ci0 = (k0 & 255) + kh * 8;
        const int R = m0 + row;
        const int nn = (R & 1023) + kz - 1;
        asrc = ((unsigned)nn < 1024u) ? (Ah_ + (size_t)(R + kz - 1) * 256 + ci0) : zbuf;
      } else {
        asrc = Ah_ + (size_t)(m0 + row) * K + k0 + kh * 8;
      }
      __builtin_amdgcn_global_load_lds(asrc, &Ah[ldsoff], 16, 0, 0);
      if constexpr (SPLIT == 3){
        const u16* asrc2 = Al_ + (size_t)(m0 + row) * K + k0 + kh * 8;
        __builtin_amdgcn_global_load_lds(asrc2, &Al[ldsoff], 16, 0, 0);
      }
    }
    // ---- stage B (BN/64 rounds) ----
#pragma unroll
    for (int r = 0; r < BN / 64; ++r){
      const int slot = r * 256 + tid;
      const int row = slot & (BN - 1), kh = slot / BN;
      const int ldsoff = (r * 256 + (tid & 192)) * 8;
      const u16* bsrc = Bh_ + (size_t)(n0 + row) * K + k0 + kh * 8;
      __builtin_amdgcn_global_load_lds(bsrc, &Bh[ldsoff], 16, 0, 0);
      if constexpr (SPLIT == 3){
        const u16* bsrc2 = Bl_ + (size_t)(n0 + row) * K + k0 + kh * 8;
        __builtin_amdgcn_global_load_lds(bsrc2, &Bl[ldsoff], 16, 0, 0);
      }
    }
    __syncthreads();
    short8 afh[MI], bfh[NJ], afl[MI], bfl[NJ];
#pragma unroll
    for (int f = 0; f < MI; ++f){
      afh[f] = *(const short8*)&Ah[(lq * BM + wr * WM + f * 16 + l15) * 8];
      if constexpr (SPLIT == 3)
        afl[f] = *(const short8*)&Al[(lq * BM + wr * WM + f * 16 + l15) * 8];
    }
#pragma unroll
    for (int f = 0; f < NJ; ++f){
      bfh[f] = *(const short8*)&Bh[(lq * BN + wc * WN + f * 16 + l15) * 8];
      if constexpr (SPLIT == 3)
        bfl[f] = *(const short8*)&Bl[(lq * BN + wc * WN + f * 16 + l15) * 8];
    }
#pragma unroll
    for (int fi = 0; fi < MI; ++fi)
#pragma unroll
      for (int fj = 0; fj < NJ; ++fj){
        acc[fi][fj] = mfma16(afh[fi], bfh[fj], acc[fi][fj]);
        if constexpr (SPLIT == 3){
          acc[fi][fj] = mfma16(afl[fi], bfh[fj], acc[fi][fj]);
          acc[fi][fj] = mfma16(afh[fi], bfl[fj], acc[fi][fj]);
        }
      }
    __syncthreads();
  }

  const int rb = m0 + wr * WM;
  const int cb = n0 + wc * WN;
  if constexpr (MODE == 0){
    u16* H = (u16*)C0v; u16* L = (u16*)C1v;
#pragma unroll
    for (int fi = 0; fi < MI; ++fi){
      const int R = rb + fi * 16 + lq * 4;
      const int nn = R & 1023, bq = R >> 10;
#pragma unroll
      for (int fj = 0; fj < NJ; ++fj){
        const int c = cb + fj * 16 + l15;
        const size_t off = (size_t)(bq * 256 + c) * 1024 + nn;
        u16 h_[4], l_[4];
#pragma unroll
        for (int r = 0; r < 4; ++r){
          float v = acc[fi][fj][r];
          u16 hi = f2bf(v); h_[r] = hi; l_[r] = f2bf(v - bf2f(hi));
        }
        st4bf(H + off, h_[0], h_[1], h_[2], h_[3]);
        st4bf(L + off, l_[0], l_[1], l_[2], l_[3]);
      }
    }
  } else if constexpr (MODE == 1){
    float* G = (float*)C0v;
#pragma unroll
    for (int fj = 0; fj < NJ; ++fj){
      const int c = cb + fj * 16 + l15;          // bo
      const int o = c & 255, bq = c >> 8;
      const float bs = bias[o];
#pragma unroll
      for (int fi = 0; fi < MI; ++fi){
        const int R = rb + fi * 16 + lq * 4;     // node n
#pragma unroll
        for (int r = 0; r < 4; ++r)
          G[((size_t)bq * 1024 + R + r) * 256 + o] = fmaxf(acc[fi][fj][r] + bs, 0.f);
      }
    }
  } else if constexpr (MODE == 2){
    u16* H = (u16*)C0v; u16* L = (u16*)C1v; u16* T = (u16*)C2v;
#pragma unroll
    for (int fi = 0; fi < MI; ++fi){
      const int R = rb + fi * 16 + lq * 4;
#pragma unroll
      for (int fj = 0; fj < NJ; ++fj){
        const int c = cb + fj * 16 + l15;
        u16 h_[4];
#pragma unroll
        for (int r = 0; r < 4; ++r){
          float v = acc[fi][fj][r];
          u16 hi = f2bf(v); h_[r] = hi;
          H[(size_t)(R + r) * 256 + c] = hi;
          L[(size_t)(R + r) * 256 + c] = f2bf(v - bf2f(hi));
        }
        st4bf(T + (size_t)c * 16384 + R, h_[0], h_[1], h_[2], h_[3]);
      }
    }
  } else {
    float* Y = (float*)C0v;
#pragma unroll
    for (int fj = 0; fj < NJ; ++fj){
      const int c = cb + fj * 16 + l15;
      const float bs = bias[c];
#pragma unroll
      for (int fi = 0; fi < MI; ++fi){
        const int R = rb + fi * 16 + lq * 4;
#pragma unroll
        for (int r = 0; r < 4; ++r)
          Y[(size_t)(R + r) * 256 + c] = acc[fi][fj][r] + bs;
      }
    }
  }
}

// Non-template wrappers (hipcc drops stubs for template __global__ in .so).
__global__ __launch_bounds__(256) void gemm0_k(
    const u16* __restrict__ Ah_, const u16* __restrict__ Bh_,
    const u16* __restrict__ zbuf, void* __restrict__ C0, void* __restrict__ C1)
{ mgemm_body<1, 128, 256, 0, 0, 128, 64, 2, 2>(Ah_, nullptr, Bh_, nullptr, zbuf, C0, C1, nullptr, nullptr); }

__global__ __launch_bounds__(256) void gemm1_k(
    const u16* __restrict__ Ah_, const u16* __restrict__ Al_,
    const u16* __restrict__ Bh_, const u16* __restrict__ Bl_,
    const u16* __restrict__ zbuf, void* __restrict__ C0, const float* __restrict__ bias)
{ mgemm_body<3, 1024, 4096, 1, 1, 64, 128, 1, 4>(Ah_, Al_, Bh_, Bl_, zbuf, C0, nullptr, nullptr, bias); }

__global__ __launch_bounds__(256) void gemm2_k(
    const u16* __restrict__ Ah_, const u16* __restrict__ Al_,
    const u16* __restrict__ Bh_, const u16* __restrict__ Bl_,
    const u16* __restrict__ zbuf,
    void* __restrict__ C0, void* __restrict__ C1, void* __restrict__ C2)
{ mgemm_body<3, 256, 256, 2, 0, 128, 64, 2, 2>(Ah_, Al_, Bh_, Bl_, zbuf, C0, C1, C2, nullptr); }

__global__ __launch_bounds__(256) void gemm3_k(
    const u16* __restrict__ Ah_, const u16* __restrict__ Bh_,
    const u16* __restrict__ zbuf, void* __restrict__ C0, const float* __restrict__ bias)
{ mgemm_body<1, 768, 256, 3, 0, 128, 64, 2, 2>(Ah_, nullptr, Bh_, nullptr, zbuf, C0, nullptr, nullptr, bias); }

// ---------------------------------------------------------------- flash GAT (MFMA)
// Grid 1024: b = bid&15 (xcd = bid%8 = b%8: 2 b's K/V = 3MB per XCD L2),
// k_ = bid>>4, h = k_>>4, qo = k_&15. Block = 64 q-rows, 4 waves x 16 rows.
// LDS 32.3KB -> 4 blocks/CU. Per 64-kv tile: K hi/lo [dk][kv][8] + V^T
// [kk][d][8]; QK^T split (6 MFMA/cell); p = exp(s-40) (exact: e <=
// max||hp||^2 ~50 by Cauchy-Schwarz, diag >= 0); P per-wave LDS [kk][q16][8];
// swapped PV out^T = Vt x P.
__global__ __launch_bounds__(256) void flash(
    const u16* __restrict__ hp_hi, const u16* __restrict__ hp_lo,
    const u16* __restrict__ hpT, u16* __restrict__ ao)
{
  __shared__ u16 Khi[4096], Klo[4096], Vt[4096];
  __shared__ u16 Pl[4][1024];
  __shared__ float Ls[4][16];
  const int tid = threadIdx.x;
  const int lane = tid & 63, l15 = lane & 15, lq = lane >> 4, w = tid >> 6;
  const int bid = blockIdx.x;
  const int b = bid & 15, k_ = bid >> 4, h = k_ >> 4, qo = k_ & 15;
  const size_t qrow0 = (size_t)b * 1024 + qo * 64 + w * 16;

  short8 qh[2], ql[2];
#pragma unroll
  for (int ks = 0; ks < 2; ++ks){
    const size_t off = (qrow0 + l15) * 256 + h * 64 + ks * 32 + lq * 8;
    qh[ks] = *(const short8*)(hp_hi + off);
    ql[ks] = *(const short8*)(hp_lo + off);
  }

  f32x4 o_[4] = {};   // out^T acc over df
  float ls[4] = {};   // row-sum partials (rows lq*4+r)

  for (int kt = 0; kt < 16; ++kt){
    const int kv0 = kt * 64;
#pragma unroll
    for (int r = 0; r < 2; ++r){
      const int slot = r * 256 + tid;
      const int g1 = slot >> 6, g2 = slot & 63;     // [g1][g2] of 8x64
      const int ldsoff = (r * 256 + (tid & 192)) * 8;
      const u16* ksrc = hp_hi + ((size_t)b * 1024 + kv0 + g2) * 256 + h * 64 + g1 * 8;
      __builtin_amdgcn_global_load_lds(ksrc, &Khi[ldsoff], 16, 0, 0);
      const u16* ksrc2 = hp_lo + ((size_t)b * 1024 + kv0 + g2) * 256 + h * 64 + g1 * 8;
      __builtin_amdgcn_global_load_lds(ksrc2, &Klo[ldsoff], 16, 0, 0);
      const u16* vsrc = hpT + (size_t)(h * 64 + g2) * 16384 + b * 1024 + kv0 + g1 * 8;
      __builtin_amdgcn_global_load_lds(vsrc, &Vt[ldsoff], 16, 0, 0);
    }
    __syncthreads();

    // QK^T + softmax numerator + P write
#pragma unroll
    for (int nf = 0; nf < 4; ++nf){
      short8 kf[2], kg[2];
#pragma unroll
      for (int ks = 0; ks < 2; ++ks){
        kf[ks] = *(const short8*)&Khi[((ks * 4 + lq) * 64 + nf * 16 + l15) * 8];
        kg[ks] = *(const short8*)&Klo[((ks * 4 + lq) * 64 + nf * 16 + l15) * 8];
      }
      const int kv = nf * 16 + l15;
      f32x4 s = {};
#pragma unroll
      for (int ks = 0; ks < 2; ++ks){
        s = mfma16(qh[ks], kf[ks], s);
        s = mfma16(ql[ks], kf[ks], s);
        s = mfma16(qh[ks], kg[ks], s);
      }
      const int base = ((kv >> 3) * 16 + lq * 4) * 8 + (kv & 7);
#pragma unroll
      for (int r = 0; r < 4; ++r){
        float v = s[r];
        v = v > 0.f ? v : 0.2f * v;                 // LeakyReLU(0.2)
        const float p = __expf(v - 40.f);           // fixed-shift numerator
        ls[r] += p;
        Pl[w][base + r * 8] = f2bf(p);
      }
    }

    // swapped PV: out^T[d][q] += A(V^T) x B(P as BT [q16][kv])
#pragma unroll
    for (int ks = 0; ks < 2; ++ks){
      short8 va[4];
#pragma unroll
      for (int f = 0; f < 4; ++f)
        va[f] = *(const short8*)&Vt[((ks * 4 + lq) * 64 + f * 16 + l15) * 8];
      const short8 pf = *(const short8*)&Pl[w][((ks * 4 + lq) * 16 + l15) * 8];
#pragma unroll
      for (int df = 0; df < 4; ++df)
        o_[df] = mfma16(va[df], pf, o_[df]);
    }
    __syncthreads();
  }

  // row-sum reduce across l15 lanes (same lq), redistribute via LDS
#pragma unroll
  for (int mask = 1; mask < 16; mask <<= 1)
#pragma unroll
    for (int i = 0; i < 4; ++i)
      ls[i] += __shfl_xor(ls[i], mask, 64);
  if (l15 == 0){
#pragma unroll
    for (int r = 0; r < 4; ++r) Ls[w][lq * 4 + r] = ls[r];
  }
  __syncthreads();
  const float inv = 1.0f / Ls[w][l15];

#pragma unroll
  for (int df = 0; df < 4; ++df){
    const size_t addr = (qrow0 + l15) * 256 + h * 64 + df * 16 + lq * 4;
    st4bf(ao + addr,
          f2bf(o_[df][0] * inv), f2bf(o_[df][1] * inv),
          f2bf(o_[df][2] * inv), f2bf(o_[df][3] * inv));
  }
}

// ---------------------------------------------------------------- BN helpers
__global__ __launch_bounds__(256) void bn_partial(const float* __restrict__ buf,
                                                  float* __restrict__ part)
{
  const int bi = blockIdx.x, t = threadIdx.x;
  const float* p = buf + (size_t)bi * 64 * 256 + t;
  float s = 0.f, q = 0.f;
#pragma unroll 4
  for (int r = 0; r < 64; ++r){ const float v = p[(size_t)r * 256]; s += v; q = fmaf(v, v, q); }
  part[bi * 512 + t] = s;
  part[bi * 512 + 256 + t] = q;
}

__global__ __launch_bounds__(256) void bn_final(const float* __restrict__ part,
                                                const float* __restrict__ gamma,
                                                const float* __restrict__ beta,
                                                float* __restrict__ prm)
{
  const int t = threadIdx.x;
  float s = 0.f, q = 0.f;
#pragma unroll 8
  for (int i = 0; i < 256; ++i){ s += part[i * 512 + t]; q += part[i * 512 + 256 + t]; }
  const float mu = s * (1.f / 16384.f);
  const float var = q * (1.f / 16384.f) - mu * mu;
  prm[t] = mu;
  prm[256 + t] = rsqrtf(var + 1e-5f) * gamma[t];
  prm[512 + t] = beta[t];
}

// BN1 apply + relu + split to bf16 hi/lo
__global__ __launch_bounds__(256) void bn_apply_split(const float* __restrict__ in,
    u16* __restrict__ H, u16* __restrict__ L, const float* __restrict__ prm)
{
  const int idx = blockIdx.x * 256 + threadIdx.x;
  const size_t off = (size_t)idx * 4;
  const int o = (int)(off & 255);
  const float4 x = ld4(in + off);
  const float4 m = ld4(prm + o), rs = ld4(prm + 256 + o), bt = ld4(prm + 512 + o);
  u16 h_[4], l_[4];
  float v;
  v = fmaxf(fmaf(x.x - m.x, rs.x, bt.x), 0.f); h_[0] = f2bf(v); l_[0] = f2bf(v - bf2f(h_[0]));
  v = fmaxf(fmaf(x.y - m.y, rs.y, bt.y), 0.f); h_[1] = f2bf(v); l_[1] = f2bf(v - bf2f(h_[1]));
  v = fmaxf(fmaf(x.z - m.z, rs.z, bt.z), 0.f); h_[2] = f2bf(v); l_[2] = f2bf(v - bf2f(h_[2]));
  v = fmaxf(fmaf(x.w - m.w, rs.w, bt.w), 0.f); h_[3] = f2bf(v); l_[3] = f2bf(v - bf2f(h_[3]));
  st4bf(H + off, h_[0], h_[1], h_[2], h_[3]);
  st4bf(L + off, l_[0], l_[1], l_[2], l_[3]);
}

// BN2 apply + relu, fp32 in-place
__global__ __launch_bounds__(256) void bn_apply(const float* __restrict__ in,
                                                float* __restrict__ outp,
                                                const float* __restrict__ prm)
{
  const int idx = blockIdx.x * 256 + threadIdx.x;
  const size_t off = (size_t)idx * 8;
  const int o = (int)(off & 255);
  const float4 x0 = ld4(in + off),      x1 = ld4(in + off + 4);
  const float4 m0 = ld4(prm + o),       m1 = ld4(prm + o + 4);
  const float4 r0 = ld4(prm + 256 + o), r1 = ld4(prm + 256 + o + 4);
  const float4 b0 = ld4(prm + 512 + o), b1 = ld4(prm + 512 + o + 4);
  float4 y0, y1;
  y0.x = fmaxf(fmaf(x0.x - m0.x, r0.x, b0.x), 0.f);
  y0.y = fmaxf(fmaf(x0.y - m0.y, r0.y, b0.y), 0.f);
  y0.z = fmaxf(fmaf(x0.z - m0.z, r0.z, b0.z), 0.f);
  y0.w = fmaxf(fmaf(x0.w - m0.w, r0.w, b0.w), 0.f);
  y1.x = fmaxf(fmaf(x1.x - m1.x, r1.x, b1.x), 0.f);
  y1.y = fmaxf(fmaf(x1.y - m1.y, r1.y, b1.y), 0.f);
  y1.z = fmaxf(fmaf(x1.z - m1.z, r1.z, b1.z), 0.f);
  y1.w = fmaxf(fmaf(x1.w - m1.w, r1.w, b1.w), 0.f);
  st4(outp + off, y0);
  st4(outp + off + 4, y1);
}

// ---------------------------------------------------------------- pack / convert
__global__ __launch_bounds__(256) void pack_w(
    const float* __restrict__ x, const float* __restrict__ adj,
    const float* __restrict__ gcw, const float* __restrict__ gatw,
    const float* __restrict__ convw,
    u16* __restrict__ xbf, u16* __restrict__ adjh, u16* __restrict__ adjl,
    u16* __restrict__ w0t, u16* __restrict__ w2th, u16* __restrict__ w2tl,
    u16* __restrict__ cwt, u16* __restrict__ zb)
{
  const int idx = blockIdx.x * 256 + threadIdx.x;
  if (idx < 2097152) xbf[idx] = f2bf(x[idx]);
  if (idx < 1048576){
    const float v = adj[idx];
    const u16 hi = f2bf(v);
    adjh[idx] = hi; adjl[idx] = f2bf(v - bf2f(hi));
  }
  if (idx < 32768){
    const int o = idx >> 7, f = idx & 127;
    w0t[idx] = f2bf(gcw[f * 256 + o]);
  }
  if (idx < 65536){
    const int c = idx >> 8, f = idx & 255;
    const float v = gatw[(c >> 6) * 16384 + f * 64 + (c & 63)];
    const u16 hi = f2bf(v);
    w2th[idx] = hi; w2tl[idx] = f2bf(v - bf2f(hi));
  }
  if (idx < 196608){
    const int co = idx / 768, k = idx - co * 768;
    const int kz = k >> 8, ci = k & 255;
    cwt[idx] = f2bf(convw[co * 768 + ci * 3 + kz]);
  }
  if (idx < 2048) zb[idx] = 0;
}

// ---------------------------------------------------------------- launch
extern "C" void kernel_launch(void* const* d_in, const int* in_sizes, int n_in,
                              void* d_out, int out_size, void* d_ws, size_t ws_size,
                              hipStream_t stream)
{
  const float* x     = (const float*)d_in[0];
  const float* adj   = (const float*)d_in[1];
  const float* gc_w  = (const float*)d_in[2];
  const float* gc_b  = (const float*)d_in[3];
  const float* bn1g  = (const float*)d_in[4];
  const float* bn1b  = (const float*)d_in[5];
  const float* gatw  = (const float*)d_in[6];
  const float* convw = (const float*)d_in[7];
  const float* convb = (const float*)d_in[8];
  const float* bn2g  = (const float*)d_in[9];
  const float* bn2b  = (const float*)d_in[10];
  char* ws  = (char*)d_ws;
  char* out = (char*)d_out;

  // ws layout (bytes), total ~25.3 MB:
  u16* h1t_hi = (u16*)(ws + 0);              // 8 MB  [bo][node]   (later: h_hi, then ao)
  u16* h1t_lo = (u16*)(ws + 8388608);        // 8 MB               (later: h_lo)
  u16* x_bf   = (u16*)(ws + 16777216);       // 4 MB               (later: hpT 8MB @16M)
  u16* adj_hi = (u16*)(ws + 20971520);       // 2 MB
  u16* adj_lo = (u16*)(ws + 23068672);       // 2 MB
  u16* hpT    = (u16*)(ws + 16777216);       // 8 MB (aliases x_bf+adj; live after both die)
  u16* w0t    = (u16*)(ws + 25165824);       // 64 KB
  u16* w2th   = (u16*)(ws + 25231360);       // 128 KB
  u16* w2tl   = (u16*)(ws + 25362432);       // 128 KB
  u16* cwt    = (u16*)(ws + 25493504);       // 384 KB
  u16* zbuf   = (u16*)(ws + 25886720);       // 4 KB zeros
  float* P1   = (float*)(ws + 25890816);     // 512 KB bn partials
  float* PR1  = (float*)(ws + 26415104);     // 3 KB
  float* PR2  = (float*)(ws + 26419200);     // 3 KB
  // aliases into ws/out across phases:
  u16* h_hi  = (u16*)(ws + 0);
  u16* h_lo  = (u16*)(ws + 8388608);
  u16* ao    = (u16*)(ws + 0);
  float* g   = (float*)out;                  // gemm1 out (16 MB), dead after bn_apply_split
  u16* hp_hi = (u16*)out;                    // gemm2 out, dead after flash
  u16* hp_lo = (u16*)(out + 8388608);
  float* y   = (float*)out;                  // gemm3 out -> bn2 in-place -> final

  pack_w<<<8192, 256, 0, stream>>>(x, adj, gc_w, gatw, convw,
                                   x_bf, adj_hi, adj_lo, w0t, w2th, w2tl, cwt, zbuf);
  // gemm0: x_bf @ w0t -> h1t hi/lo   (128x64 tiles, 512 blocks)
  gemm0_k<<<dim3(4, 128), 256, 0, stream>>>(x_bf, w0t, zbuf, h1t_hi, h1t_lo);
  // gemm1 (split): adj @ h1t -> g (+gc_b, relu). 64x128 tiles, m on x (XCD owns adj panels).
  gemm1_k<<<dim3(16, 32), 256, 0, stream>>>(adj_hi, adj_lo, h1t_hi, h1t_lo, zbuf, g, gc_b);
  bn_partial<<<256, 256, 0, stream>>>(g, P1);
  bn_final<<<1, 256, 0, stream>>>(P1, bn1g, bn1b, PR1);
  bn_apply_split<<<4096, 256, 0, stream>>>(g, h_hi, h_lo, PR1);
  // gemm2 (split): h @ w2t -> hp hi/lo + hpT   (128x64 tiles, 512 blocks)
  gemm2_k<<<dim3(4, 128), 256, 0, stream>>>(h_hi, h_lo, w2th, w2tl, zbuf, hp_hi, hp_lo, hpT);
  // flash GAT (1024 blocks, 4/CU)
  flash<<<1024, 256, 0, stream>>>(hp_hi, hp_lo, hpT, ao);
  // gemm3: im2col(ao) @ cwt -> y (+conv_b)   (128x64 tiles, 512 blocks)
  gemm3_k<<<dim3(4, 128), 256, 0, stream>>>(ao, cwt, zbuf, y, convb);
  bn_partial<<<256, 256, 0, stream>>>(y, P1);
  bn_final<<<1, 256, 0, stream>>>(P1, bn2g, bn2b, PR2);
  bn_apply<<<2048, 256, 0, stream>>>(y, y, PR2);
}

// Round 9
// 301.491 us; speedup vs baseline: 2.5752x; 1.0438x over previous
//
#include <hip/hip_runtime.h>
#include <hip/hip_bf16.h>

// GCN + MultiHead GAT + TCN — bf16 MFMA pipeline with split-precision paths.
// B=16, N=1024, NFEAT=128, NHID=256, NOUT=256, H=4, DH=64.
//
// Round 7 -> 8:
//  * flash mf=1 regressed (DS-bound: MFMA/tile halved, LDS reads ~constant).
//    Revert to 512 blocks x 128 q-rows (mf=2, LDS 40.5KB, 3 blocks/CU).
//  * BN stats fused into gemm1/gemm3 epilogues (deterministic per-block
//    partial slots, shfl_xor over lq); bn_partial kernels dropped (12->10
//    launches). One shared bn_final folds 256 slots for both BNs.
//  * gemm1 emits g as bf16 hi/lo (stats from fp32 acc first) -> halves
//    g write + bn_apply_split read traffic.
//
// Precision plan: gemm0 plain bf16; gemm1 SPLIT hi/lo both sides (BN1
// amplifies pre-BN error ~100x); gemm2 SPLIT; flash QK^T SPLIT; flash PV
// plain (P in [0,1], sum=1); gemm3 plain.
// MFMA: v_mfma_f32_16x16x32_bf16. A[row=l&15][k=(l>>4)*8+i], B likewise on BT
// storage, D[col=l&15][row=(l>>4)*4+reg] (m89-verified).
// LDS tiles [k/8][row][8] staged via global_load_lds(16B), per-lane permuted
// global source (m173), wave-uniform LDS base.

typedef unsigned short u16;
typedef __attribute__((ext_vector_type(8))) short short8;  // 8 bf16 = 4 VGPR
typedef __attribute__((ext_vector_type(4))) float f32x4;

static __device__ __forceinline__ float4 ld4(const float* p){ return *(const float4*)p; }
static __device__ __forceinline__ void st4(float* p, float4 v){ *(float4*)p = v; }

static __device__ __forceinline__ u16 f2bf(float f){           // RNE
  unsigned u = __builtin_bit_cast(unsigned, f);
  unsigned r = u + 0x7FFFu + ((u >> 16) & 1u);
  return (u16)(r >> 16);
}
static __device__ __forceinline__ float bf2f(u16 h){
  unsigned u = ((unsigned)h) << 16; return __builtin_bit_cast(float, u);
}
static __device__ __forceinline__ void st4bf(u16* p, u16 a, u16 b, u16 c, u16 d){
  uint2 v; v.x = (unsigned)a | ((unsigned)b << 16); v.y = (unsigned)c | ((unsigned)d << 16);
  *(uint2*)p = v;
}
static __device__ __forceinline__ f32x4 mfma16(short8 a, short8 b, f32x4 c){
  return __builtin_amdgcn_mfma_f32_16x16x32_bf16(a, b, c, 0, 0, 0);
}

// ---------------------------------------------------------------- MFMA GEMM body
// A [M][K] bf16 row-major (hi/lo), B as BT [NN][K] bf16 (hi/lo).
// Tile BM x BN, 4 waves as WR x WC grid; wave tile (BM/WR)x(BN/WC).
// AXSWAP: m on blockIdx.x (XCD owns adj m-panels for gemm1).
// MODE 0: gemm0 -> h1t hi/lo scatter [bo][node]
// MODE 1: gemm1 -> g bf16 hi/lo [(bq*1024+n)*256+o] + relu + fused BN partials
// MODE 2: gemm2 -> hp hi/lo [R][256] + hpT (hi) [256][16384]
// MODE 3: gemm3 (im2col A, zbuf pad) -> y fp32 + conv_b + fused BN partials
template<int SPLIT, int K, int NN, int MODE, int AXSWAP, int BM, int BN, int WR, int WC>
static __device__ __forceinline__ void mgemm_body(
    const u16* __restrict__ Ah_, const u16* __restrict__ Al_,
    const u16* __restrict__ Bh_, const u16* __restrict__ Bl_,
    const u16* __restrict__ zbuf,
    void* __restrict__ C0v, void* __restrict__ C1v, void* __restrict__ C2v,
    const float* __restrict__ bias)
{
  constexpr int KT = K / 32;
  constexpr int WM = BM / WR, WN = BN / WC;
  constexpr int MI = WM / 16, NJ = WN / 16;
  __shared__ u16 Ah[BM * 32], Bh[BN * 32];
  __shared__ u16 Al[SPLIT == 3 ? BM * 32 : 8], Bl[SPLIT == 3 ? BN * 32 : 8];
  const int tid = threadIdx.x;
  const int n0 = (AXSWAP ? blockIdx.y : blockIdx.x) * BN;
  const int m0 = (AXSWAP ? blockIdx.x : blockIdx.y) * BM;
  const int lane = tid & 63, l15 = lane & 15, lq = lane >> 4;
  const int w = tid >> 6, wr = w / WC, wc = w % WC;

  f32x4 acc[MI][NJ] = {};

  for (int kt = 0; kt < KT; ++kt){
    const int k0 = kt * 32;
    // ---- stage A (BM/64 rounds of 4KB) ----
#pragma unroll
    for (int r = 0; r < BM / 64; ++r){
      const int slot = r * 256 + tid;
      const int row = slot & (BM - 1), kh = slot / BM;
      const int ldsoff = (r * 256 + (tid & 192)) * 8;   // wave-uniform; lane adds 16B
      const u16* asrc;
      if constexpr (MODE == 3){
        const int kz = k0 >> 8;
        const int ci0 = (k0 & 255) + kh * 8;
        const int R = m0 + row;
        const int nn = (R & 1023) + kz - 1;
        asrc = ((unsigned)nn < 1024u) ? (Ah_ + (size_t)(R + kz - 1) * 256 + ci0) : zbuf;
      } else {
        asrc = Ah_ + (size_t)(m0 + row) * K + k0 + kh * 8;
      }
      __builtin_amdgcn_global_load_lds(asrc, &Ah[ldsoff], 16, 0, 0);
      if constexpr (SPLIT == 3){
        const u16* asrc2 = Al_ + (size_t)(m0 + row) * K + k0 + kh * 8;
        __builtin_amdgcn_global_load_lds(asrc2, &Al[ldsoff], 16, 0, 0);
      }
    }
    // ---- stage B (BN/64 rounds) ----
#pragma unroll
    for (int r = 0; r < BN / 64; ++r){
      const int slot = r * 256 + tid;
      const int row = slot & (BN - 1), kh = slot / BN;
      const int ldsoff = (r * 256 + (tid & 192)) * 8;
      const u16* bsrc = Bh_ + (size_t)(n0 + row) * K + k0 + kh * 8;
      __builtin_amdgcn_global_load_lds(bsrc, &Bh[ldsoff], 16, 0, 0);
      if constexpr (SPLIT == 3){
        const u16* bsrc2 = Bl_ + (size_t)(n0 + row) * K + k0 + kh * 8;
        __builtin_amdgcn_global_load_lds(bsrc2, &Bl[ldsoff], 16, 0, 0);
      }
    }
    __syncthreads();
    short8 afh[MI], bfh[NJ], afl[MI], bfl[NJ];
#pragma unroll
    for (int f = 0; f < MI; ++f){
      afh[f] = *(const short8*)&Ah[(lq * BM + wr * WM + f * 16 + l15) * 8];
      if constexpr (SPLIT == 3)
        afl[f] = *(const short8*)&Al[(lq * BM + wr * WM + f * 16 + l15) * 8];
    }
#pragma unroll
    for (int f = 0; f < NJ; ++f){
      bfh[f] = *(const short8*)&Bh[(lq * BN + wc * WN + f * 16 + l15) * 8];
      if constexpr (SPLIT == 3)
        bfl[f] = *(const short8*)&Bl[(lq * BN + wc * WN + f * 16 + l15) * 8];
    }
#pragma unroll
    for (int fi = 0; fi < MI; ++fi)
#pragma unroll
      for (int fj = 0; fj < NJ; ++fj){
        acc[fi][fj] = mfma16(afh[fi], bfh[fj], acc[fi][fj]);
        if constexpr (SPLIT == 3){
          acc[fi][fj] = mfma16(afl[fi], bfh[fj], acc[fi][fj]);
          acc[fi][fj] = mfma16(afh[fi], bfl[fj], acc[fi][fj]);
        }
      }
    __syncthreads();
  }

  const int rb = m0 + wr * WM;
  const int cb = n0 + wc * WN;
  if constexpr (MODE == 0){
    u16* H = (u16*)C0v; u16* L = (u16*)C1v;
#pragma unroll
    for (int fi = 0; fi < MI; ++fi){
      const int R = rb + fi * 16 + lq * 4;
      const int nn = R & 1023, bq = R >> 10;
#pragma unroll
      for (int fj = 0; fj < NJ; ++fj){
        const int c = cb + fj * 16 + l15;
        const size_t off = (size_t)(bq * 256 + c) * 1024 + nn;
        u16 h_[4], l_[4];
#pragma unroll
        for (int r = 0; r < 4; ++r){
          float v = acc[fi][fj][r];
          u16 hi = f2bf(v); h_[r] = hi; l_[r] = f2bf(v - bf2f(hi));
        }
        st4bf(H + off, h_[0], h_[1], h_[2], h_[3]);
        st4bf(L + off, l_[0], l_[1], l_[2], l_[3]);
      }
    }
  } else if constexpr (MODE == 1){
    // g = relu(acc+bias) -> bf16 hi/lo; fused BN1 partials (exact fp32 stats).
    u16* GH = (u16*)C0v; u16* GL = (u16*)C1v; float* PT = (float*)C2v;
    const int mb = AXSWAP ? blockIdx.x : blockIdx.y;   // 16 m-blocks of 64 rows
#pragma unroll
    for (int fj = 0; fj < NJ; ++fj){
      const int c = cb + fj * 16 + l15;          // bo-space col
      const int o = c & 255, bq = c >> 8;
      const float bs = bias[o];
      float s = 0.f, q = 0.f;
#pragma unroll
      for (int fi = 0; fi < MI; ++fi){
        const int R = rb + fi * 16 + lq * 4;     // node n
#pragma unroll
        for (int r = 0; r < 4; ++r){
          const float v = fmaxf(acc[fi][fj][r] + bs, 0.f);
          s += v; q = fmaf(v, v, q);
          const u16 hi = f2bf(v);
          const size_t off = ((size_t)bq * 1024 + R + r) * 256 + o;
          GH[off] = hi;
          GL[off] = f2bf(v - bf2f(hi));
        }
      }
      // WR==1: one wave covers all 64 rows of this col; fold lq groups.
      s += __shfl_xor(s, 16, 64); s += __shfl_xor(s, 32, 64);
      q += __shfl_xor(q, 16, 64); q += __shfl_xor(q, 32, 64);
      if (lq == 0){
        PT[mb * 4096 + c]         = s;
        PT[65536 + mb * 4096 + c] = q;
      }
    }
  } else if constexpr (MODE == 2){
    u16* H = (u16*)C0v; u16* L = (u16*)C1v; u16* T = (u16*)C2v;
#pragma unroll
    for (int fi = 0; fi < MI; ++fi){
      const int R = rb + fi * 16 + lq * 4;
#pragma unroll
      for (int fj = 0; fj < NJ; ++fj){
        const int c = cb + fj * 16 + l15;
        u16 h_[4];
#pragma unroll
        for (int r = 0; r < 4; ++r){
          float v = acc[fi][fj][r];
          u16 hi = f2bf(v); h_[r] = hi;
          H[(size_t)(R + r) * 256 + c] = hi;
          L[(size_t)(R + r) * 256 + c] = f2bf(v - bf2f(hi));
        }
        st4bf(T + (size_t)c * 16384 + R, h_[0], h_[1], h_[2], h_[3]);
      }
    }
  } else {
    // y = acc + conv_b (fp32, pre-relu: BN2 stats are over y); fused partials.
    float* Y = (float*)C0v; float* PT = (float*)C2v;
    const int slot = blockIdx.y * 2 + wr;        // 256 row-slots of 64 rows
#pragma unroll
    for (int fj = 0; fj < NJ; ++fj){
      const int c = cb + fj * 16 + l15;
      const float bs = bias[c];
      float s = 0.f, q = 0.f;
#pragma unroll
      for (int fi = 0; fi < MI; ++fi){
        const int R = rb + fi * 16 + lq * 4;
#pragma unroll
        for (int r = 0; r < 4; ++r){
          const float v = acc[fi][fj][r] + bs;
          s += v; q = fmaf(v, v, q);
          Y[(size_t)(R + r) * 256 + c] = v;
        }
      }
      s += __shfl_xor(s, 16, 64); s += __shfl_xor(s, 32, 64);
      q += __shfl_xor(q, 16, 64); q += __shfl_xor(q, 32, 64);
      if (lq == 0){
        PT[slot * 256 + c]         = s;
        PT[65536 + slot * 256 + c] = q;
      }
    }
  }
}

// Non-template wrappers (hipcc drops stubs for template __global__ in .so).
__global__ __launch_bounds__(256) void gemm0_k(
    const u16* __restrict__ Ah_, const u16* __restrict__ Bh_,
    const u16* __restrict__ zbuf, void* __restrict__ C0, void* __restrict__ C1)
{ mgemm_body<1, 128, 256, 0, 0, 128, 64, 2, 2>(Ah_, nullptr, Bh_, nullptr, zbuf, C0, C1, nullptr, nullptr); }

__global__ __launch_bounds__(256) void gemm1_k(
    const u16* __restrict__ Ah_, const u16* __restrict__ Al_,
    const u16* __restrict__ Bh_, const u16* __restrict__ Bl_,
    const u16* __restrict__ zbuf, void* __restrict__ C0, void* __restrict__ C1,
    void* __restrict__ C2, const float* __restrict__ bias)
{ mgemm_body<3, 1024, 4096, 1, 1, 64, 128, 1, 4>(Ah_, Al_, Bh_, Bl_, zbuf, C0, C1, C2, bias); }

__global__ __launch_bounds__(256) void gemm2_k(
    const u16* __restrict__ Ah_, const u16* __restrict__ Al_,
    const u16* __restrict__ Bh_, const u16* __restrict__ Bl_,
    const u16* __restrict__ zbuf,
    void* __restrict__ C0, void* __restrict__ C1, void* __restrict__ C2)
{ mgemm_body<3, 256, 256, 2, 0, 128, 64, 2, 2>(Ah_, Al_, Bh_, Bl_, zbuf, C0, C1, C2, nullptr); }

__global__ __launch_bounds__(256) void gemm3_k(
    const u16* __restrict__ Ah_, const u16* __restrict__ Bh_,
    const u16* __restrict__ zbuf, void* __restrict__ C0, void* __restrict__ C2,
    const float* __restrict__ bias)
{ mgemm_body<1, 768, 256, 3, 0, 128, 64, 2, 2>(Ah_, nullptr, Bh_, nullptr, zbuf, C0, nullptr, C2, bias); }

// ---------------------------------------------------------------- flash GAT (MFMA)
// Round-6 geometry (proven): grid 512, b = bid&15 (xcd = b%8), k_ = bid>>4,
// h = k_>>3, qo = k_&7. Block = 128 q-rows, 4 waves x 32 rows (mf=2).
// LDS 40.5KB -> 3 blocks/CU. Per 64-kv tile: K hi/lo [dk][kv][8] + V^T
// [kk][d][8]; QK^T split (6 MFMA/cell); p = exp(s-40) (exact: e <=
// max||hp||^2 ~50 by Cauchy-Schwarz, diag >= 0); P per-wave LDS [kk][q32][8];
// swapped PV out^T = Vt x P.
__global__ __launch_bounds__(256) void flash(
    const u16* __restrict__ hp_hi, const u16* __restrict__ hp_lo,
    const u16* __restrict__ hpT, u16* __restrict__ ao)
{
  __shared__ u16 Khi[4096], Klo[4096], Vt[4096];
  __shared__ u16 Pl[4][2048];
  __shared__ float Ls[4][32];
  const int tid = threadIdx.x;
  const int lane = tid & 63, l15 = lane & 15, lq = lane >> 4, w = tid >> 6;
  const int bid = blockIdx.x;
  const int b = bid & 15, k_ = bid >> 4, h = k_ >> 3, qo = k_ & 7;
  const size_t qrow0 = (size_t)b * 1024 + qo * 128 + w * 32;

  short8 qh[2][2], ql[2][2];
#pragma unroll
  for (int mf = 0; mf < 2; ++mf)
#pragma unroll
    for (int ks = 0; ks < 2; ++ks){
      const size_t off = (qrow0 + mf * 16 + l15) * 256 + h * 64 + ks * 32 + lq * 8;
      qh[mf][ks] = *(const short8*)(hp_hi + off);
      ql[mf][ks] = *(const short8*)(hp_lo + off);
    }

  f32x4 o_[4][2] = {};   // out^T acc: [df][qf]
  float ls[8] = {};      // row-sum partials: [mf*4+r]

  for (int kt = 0; kt < 16; ++kt){
    const int kv0 = kt * 64;
#pragma unroll
    for (int r = 0; r < 2; ++r){
      const int slot = r * 256 + tid;
      const int g1 = slot >> 6, g2 = slot & 63;     // [g1][g2] of 8x64
      const int ldsoff = (r * 256 + (tid & 192)) * 8;
      const u16* ksrc = hp_hi + ((size_t)b * 1024 + kv0 + g2) * 256 + h * 64 + g1 * 8;
      __builtin_amdgcn_global_load_lds(ksrc, &Khi[ldsoff], 16, 0, 0);
      const u16* ksrc2 = hp_lo + ((size_t)b * 1024 + kv0 + g2) * 256 + h * 64 + g1 * 8;
      __builtin_amdgcn_global_load_lds(ksrc2, &Klo[ldsoff], 16, 0, 0);
      const u16* vsrc = hpT + (size_t)(h * 64 + g2) * 16384 + b * 1024 + kv0 + g1 * 8;
      __builtin_amdgcn_global_load_lds(vsrc, &Vt[ldsoff], 16, 0, 0);
    }
    __syncthreads();

    // QK^T + softmax numerator + P write
#pragma unroll
    for (int nf = 0; nf < 4; ++nf){
      short8 kf[2], kg[2];
#pragma unroll
      for (int ks = 0; ks < 2; ++ks){
        kf[ks] = *(const short8*)&Khi[((ks * 4 + lq) * 64 + nf * 16 + l15) * 8];
        kg[ks] = *(const short8*)&Klo[((ks * 4 + lq) * 64 + nf * 16 + l15) * 8];
      }
      const int kv = nf * 16 + l15;
#pragma unroll
      for (int mf = 0; mf < 2; ++mf){
        f32x4 s = {};
#pragma unroll
        for (int ks = 0; ks < 2; ++ks){
          s = mfma16(qh[mf][ks], kf[ks], s);
          s = mfma16(ql[mf][ks], kf[ks], s);
          s = mfma16(qh[mf][ks], kg[ks], s);
        }
        const int qb = mf * 16 + lq * 4;
        const int base = ((kv >> 3) * 32 + qb) * 8 + (kv & 7);
#pragma unroll
        for (int r = 0; r < 4; ++r){
          float v = s[r];
          v = v > 0.f ? v : 0.2f * v;                 // LeakyReLU(0.2)
          const float p = __expf(v - 40.f);           // fixed-shift numerator
          ls[mf * 4 + r] += p;
          Pl[w][base + r * 8] = f2bf(p);
        }
      }
    }

    // swapped PV: out^T[d][q] += A(V^T) x B(P as BT [q32][kv])
#pragma unroll
    for (int ks = 0; ks < 2; ++ks){
      short8 va[4], pf[2];
#pragma unroll
      for (int f = 0; f < 4; ++f)
        va[f] = *(const short8*)&Vt[((ks * 4 + lq) * 64 + f * 16 + l15) * 8];
#pragma unroll
      for (int f = 0; f < 2; ++f)
        pf[f] = *(const short8*)&Pl[w][((ks * 4 + lq) * 32 + f * 16 + l15) * 8];
#pragma unroll
      for (int df = 0; df < 4; ++df)
#pragma unroll
        for (int qf = 0; qf < 2; ++qf)
          o_[df][qf] = mfma16(va[df], pf[qf], o_[df][qf]);
    }
    __syncthreads();
  }

  // row-sum reduce across l15 groups, redistribute via LDS
#pragma unroll
  for (int mask = 1; mask < 16; mask <<= 1)
#pragma unroll
    for (int i = 0; i < 8; ++i)
      ls[i] += __shfl_xor(ls[i], mask, 64);
  if (l15 == 0){
#pragma unroll
    for (int mf = 0; mf < 2; ++mf)
#pragma unroll
      for (int r = 0; r < 4; ++r)
        Ls[w][mf * 16 + lq * 4 + r] = ls[mf * 4 + r];
  }
  __syncthreads();
  float inv[2];
#pragma unroll
  for (int qf = 0; qf < 2; ++qf) inv[qf] = 1.0f / Ls[w][qf * 16 + l15];

#pragma unroll
  for (int qf = 0; qf < 2; ++qf)
#pragma unroll
    for (int df = 0; df < 4; ++df){
      const size_t addr = (qrow0 + qf * 16 + l15) * 256 + h * 64 + df * 16 + lq * 4;
      st4bf(ao + addr,
            f2bf(o_[df][qf][0] * inv[qf]), f2bf(o_[df][qf][1] * inv[qf]),
            f2bf(o_[df][qf][2] * inv[qf]), f2bf(o_[df][qf][3] * inv[qf]));
    }
}

// ---------------------------------------------------------------- BN helpers
// Fold 256 partial slots (layout: sum[i*256+t], sumsq at +65536) -> prm.
__global__ __launch_bounds__(256) void bn_final(const float* __restrict__ part,
                                                const float* __restrict__ gamma,
                                                const float* __restrict__ beta,
                                                float* __restrict__ prm)
{
  const int t = threadIdx.x;
  float s = 0.f, q = 0.f;
#pragma unroll 8
  for (int i = 0; i < 256; ++i){ s += part[i * 256 + t]; q += part[65536 + i * 256 + t]; }
  const float mu = s * (1.f / 16384.f);
  const float var = q * (1.f / 16384.f) - mu * mu;
  prm[t] = mu;
  prm[256 + t] = rsqrtf(var + 1e-5f) * gamma[t];
  prm[512 + t] = beta[t];
}

// BN1 apply + relu: reads g as bf16 hi/lo, emits h hi/lo.
__global__ __launch_bounds__(256) void bn_apply_split(
    const u16* __restrict__ GH, const u16* __restrict__ GL,
    u16* __restrict__ H, u16* __restrict__ L, const float* __restrict__ prm)
{
  const int idx = blockIdx.x * 256 + threadIdx.x;
  const size_t off = (size_t)idx * 4;
  const int o = (int)(off & 255);
  const uint2 hv = *(const uint2*)(GH + off);
  const uint2 lv = *(const uint2*)(GL + off);
  const float4 m = ld4(prm + o), rs = ld4(prm + 256 + o), bt = ld4(prm + 512 + o);
  float x0 = bf2f((u16)(hv.x & 0xffff)) + bf2f((u16)(lv.x & 0xffff));
  float x1 = bf2f((u16)(hv.x >> 16))    + bf2f((u16)(lv.x >> 16));
  float x2 = bf2f((u16)(hv.y & 0xffff)) + bf2f((u16)(lv.y & 0xffff));
  float x3 = bf2f((u16)(hv.y >> 16))    + bf2f((u16)(lv.y >> 16));
  u16 h_[4], l_[4];
  float v;
  v = fmaxf(fmaf(x0 - m.x, rs.x, bt.x), 0.f); h_[0] = f2bf(v); l_[0] = f2bf(v - bf2f(h_[0]));
  v = fmaxf(fmaf(x1 - m.y, rs.y, bt.y), 0.f); h_[1] = f2bf(v); l_[1] = f2bf(v - bf2f(h_[1]));
  v = fmaxf(fmaf(x2 - m.z, rs.z, bt.z), 0.f); h_[2] = f2bf(v); l_[2] = f2bf(v - bf2f(h_[2]));
  v = fmaxf(fmaf(x3 - m.w, rs.w, bt.w), 0.f); h_[3] = f2bf(v); l_[3] = f2bf(v - bf2f(h_[3]));
  st4bf(H + off, h_[0], h_[1], h_[2], h_[3]);
  st4bf(L + off, l_[0], l_[1], l_[2], l_[3]);
}

// BN2 apply + relu, fp32 in-place
__global__ __launch_bounds__(256) void bn_apply(const float* __restrict__ in,
                                                float* __restrict__ outp,
                                                const float* __restrict__ prm)
{
  const int idx = blockIdx.x * 256 + threadIdx.x;
  const size_t off = (size_t)idx * 8;
  const int o = (int)(off & 255);
  const float4 x0 = ld4(in + off),      x1 = ld4(in + off + 4);
  const float4 m0 = ld4(prm + o),       m1 = ld4(prm + o + 4);
  const float4 r0 = ld4(prm + 256 + o), r1 = ld4(prm + 256 + o + 4);
  const float4 b0 = ld4(prm + 512 + o), b1 = ld4(prm + 512 + o + 4);
  float4 y0, y1;
  y0.x = fmaxf(fmaf(x0.x - m0.x, r0.x, b0.x), 0.f);
  y0.y = fmaxf(fmaf(x0.y - m0.y, r0.y, b0.y), 0.f);
  y0.z = fmaxf(fmaf(x0.z - m0.z, r0.z, b0.z), 0.f);
  y0.w = fmaxf(fmaf(x0.w - m0.w, r0.w, b0.w), 0.f);
  y1.x = fmaxf(fmaf(x1.x - m1.x, r1.x, b1.x), 0.f);
  y1.y = fmaxf(fmaf(x1.y - m1.y, r1.y, b1.y), 0.f);
  y1.z = fmaxf(fmaf(x1.z - m1.z, r1.z, b1.z), 0.f);
  y1.w = fmaxf(fmaf(x1.w - m1.w, r1.w, b1.w), 0.f);
  st4(outp + off, y0);
  st4(outp + off + 4, y1);
}

// ---------------------------------------------------------------- pack / convert
__global__ __launch_bounds__(256) void pack_w(
    const float* __restrict__ x, const float* __restrict__ adj,
    const float* __restrict__ gcw, const float* __restrict__ gatw,
    const float* __restrict__ convw,
    u16* __restrict__ xbf, u16* __restrict__ adjh, u16* __restrict__ adjl,
    u16* __restrict__ w0t, u16* __restrict__ w2th, u16* __restrict__ w2tl,
    u16* __restrict__ cwt, u16* __restrict__ zb)
{
  const int idx = blockIdx.x * 256 + threadIdx.x;
  if (idx < 2097152) xbf[idx] = f2bf(x[idx]);
  if (idx < 1048576){
    const float v = adj[idx];
    const u16 hi = f2bf(v);
    adjh[idx] = hi; adjl[idx] = f2bf(v - bf2f(hi));
  }
  if (idx < 32768){
    const int o = idx >> 7, f = idx & 127;
    w0t[idx] = f2bf(gcw[f * 256 + o]);
  }
  if (idx < 65536){
    const int c = idx >> 8, f = idx & 255;
    const float v = gatw[(c >> 6) * 16384 + f * 64 + (c & 63)];
    const u16 hi = f2bf(v);
    w2th[idx] = hi; w2tl[idx] = f2bf(v - bf2f(hi));
  }
  if (idx < 196608){
    const int co = idx / 768, k = idx - co * 768;
    const int kz = k >> 8, ci = k & 255;
    cwt[idx] = f2bf(convw[co * 768 + ci * 3 + kz]);
  }
  if (idx < 2048) zb[idx] = 0;
}

// ---------------------------------------------------------------- launch
extern "C" void kernel_launch(void* const* d_in, const int* in_sizes, int n_in,
                              void* d_out, int out_size, void* d_ws, size_t ws_size,
                              hipStream_t stream)
{
  const float* x     = (const float*)d_in[0];
  const float* adj   = (const float*)d_in[1];
  const float* gc_w  = (const float*)d_in[2];
  const float* gc_b  = (const float*)d_in[3];
  const float* bn1g  = (const float*)d_in[4];
  const float* bn1b  = (const float*)d_in[5];
  const float* gatw  = (const float*)d_in[6];
  const float* convw = (const float*)d_in[7];
  const float* convb = (const float*)d_in[8];
  const float* bn2g  = (const float*)d_in[9];
  const float* bn2b  = (const float*)d_in[10];
  char* ws  = (char*)d_ws;
  char* out = (char*)d_out;

  // ws layout (bytes), total ~25.3 MB:
  u16* h1t_hi = (u16*)(ws + 0);              // 8 MB  [bo][node]   (later: h_hi, then ao)
  u16* h1t_lo = (u16*)(ws + 8388608);        // 8 MB               (later: h_lo)
  u16* x_bf   = (u16*)(ws + 16777216);       // 4 MB               (later: hpT 8MB @16M)
  u16* adj_hi = (u16*)(ws + 20971520);       // 2 MB
  u16* adj_lo = (u16*)(ws + 23068672);       // 2 MB
  u16* hpT    = (u16*)(ws + 16777216);       // 8 MB (aliases x_bf+adj; live after both die)
  u16* w0t    = (u16*)(ws + 25165824);       // 64 KB
  u16* w2th   = (u16*)(ws + 25231360);       // 128 KB
  u16* w2tl   = (u16*)(ws + 25362432);       // 128 KB
  u16* cwt    = (u16*)(ws + 25493504);       // 384 KB
  u16* zbuf   = (u16*)(ws + 25886720);       // 4 KB zeros
  float* P1   = (float*)(ws + 25890816);     // 512 KB bn partial slots (sum | sumsq)
  float* PR1  = (float*)(ws + 26415104);     // 3 KB
  float* PR2  = (float*)(ws + 26419200);     // 3 KB
  // aliases into ws/out across phases:
  u16* h_hi  = (u16*)(ws + 0);
  u16* h_lo  = (u16*)(ws + 8388608);
  u16* ao    = (u16*)(ws + 0);
  u16* g_hi  = (u16*)out;                    // gemm1 out hi (8 MB), dead after bn_apply_split
  u16* g_lo  = (u16*)(out + 8388608);        // gemm1 out lo (8 MB)
  u16* hp_hi = (u16*)out;                    // gemm2 out, dead after flash
  u16* hp_lo = (u16*)(out + 8388608);
  float* y   = (float*)out;                  // gemm3 out -> bn2 in-place -> final

  pack_w<<<8192, 256, 0, stream>>>(x, adj, gc_w, gatw, convw,
                                   x_bf, adj_hi, adj_lo, w0t, w2th, w2tl, cwt, zbuf);
  // gemm0: x_bf @ w0t -> h1t hi/lo   (128x64 tiles, 512 blocks)
  gemm0_k<<<dim3(4, 128), 256, 0, stream>>>(x_bf, w0t, zbuf, h1t_hi, h1t_lo);
  // gemm1 (split): adj @ h1t -> g hi/lo (+gc_b, relu) + BN1 partials. m on x.
  gemm1_k<<<dim3(16, 32), 256, 0, stream>>>(adj_hi, adj_lo, h1t_hi, h1t_lo, zbuf,
                                            g_hi, g_lo, P1, gc_b);
  bn_final<<<1, 256, 0, stream>>>(P1, bn1g, bn1b, PR1);
  bn_apply_split<<<4096, 256, 0, stream>>>(g_hi, g_lo, h_hi, h_lo, PR1);
  // gemm2 (split): h @ w2t -> hp hi/lo + hpT   (128x64 tiles, 512 blocks)
  gemm2_k<<<dim3(4, 128), 256, 0, stream>>>(h_hi, h_lo, w2th, w2tl, zbuf, hp_hi, hp_lo, hpT);
  // flash GAT (512 blocks x 128 q-rows, 3/CU)
  flash<<<512, 256, 0, stream>>>(hp_hi, hp_lo, hpT, ao);
  // gemm3: im2col(ao) @ cwt -> y fp32 (+conv_b) + BN2 partials
  gemm3_k<<<dim3(4, 128), 256, 0, stream>>>(ao, cwt, zbuf, y, P1, convb);
  bn_final<<<1, 256, 0, stream>>>(P1, bn2g, bn2b, PR2);
  bn_apply<<<2048, 256, 0, stream>>>(y, y, PR2);
}